// Round 5
// baseline (553.323 us; speedup 1.0000x reference)
//
#include <hip/hip_runtime.h>
#include <hip/hip_bf16.h>
#include <math.h>

typedef __hip_bfloat16 bf16;

#define DIMD 128
#define BB 8
#define LL 128
#define TT 512

// esym tile params
#define BMT 64
#define BKT 32
#define TGT_TILES 36   // 8*9/2 upper-tri tiles (N=512 / 64)
#define LIG_TILES 3    // 2*3/2 upper-tri tiles (N=128 / 64)

// Runtime-dtype load of external inputs: bf==1 -> bf16, else f32.
__device__ __forceinline__ float LD(const void* p, long i, int bf) {
    if (bf) return __bfloat162float(((const bf16*)p)[i]);
    return ((const float*)p)[i];
}

// Detect external dtype from emb_W bit patterns + zero the accumulators.
__global__ void init_ws(const unsigned int* __restrict__ embw_raw,
                        float* __restrict__ accum, int* __restrict__ flagp) {
    int t = threadIdx.x;
    if (t < 32) accum[t] = 0.0f;
    if (t == 0) {
        int cnt = 0;
        for (int k = 0; k < 256; ++k) {
            unsigned int b = (embw_raw[k] >> 8) & 0xffu;
            unsigned int e = b & 0x7fu;
            if (e >= 0x38u && e <= 0x3fu) ++cnt;
        }
        *flagp = (cnt > 128) ? 1 : 0;
    }
}

// Both-sides embedding: rows [0, BB*LL) from Xl, rest from Xt. K=54.
__global__ void embed_both(const void* __restrict__ Xl, const void* __restrict__ Xt,
                           const void* __restrict__ W, float* __restrict__ out,
                           int K, const int* __restrict__ flagp) {
    __shared__ float xrow[DIMD];
    int bf = *flagp;
    int row = blockIdx.x;
    int d = threadIdx.x;
    const void* X; long r;
    if (row < BB * LL) { X = Xl; r = row; }
    else               { X = Xt; r = row - BB * LL; }
    if (d < K) xrow[d] = LD(X, r * K + d, bf);
    __syncthreads();
    float acc = 0.0f;
    for (int k = 0; k < K; ++k)
        acc = fmaf(xrow[k], LD(W, (long)k * DIMD + d, bf), acc);
    out[(long)row * DIMD + d] = acc;
}

// Fused h = x@W + Wb  and  hA = h@A  (row-local chain; h staged in LDS).
// 8 rows/block, 256 threads (2 row-groups x 128 cols). Same weights both sides.
__global__ void gemm_hha(const float* __restrict__ X, const void* __restrict__ W,
                         const void* __restrict__ A, long offW,
                         const void* __restrict__ Wb, long offWb,
                         float* __restrict__ hout, float* __restrict__ hAout,
                         const int* __restrict__ flagp) {
    __shared__ float xs[8][DIMD];
    __shared__ float hs[8][DIMD];
    int bf = *flagp;
    long row0 = (long)blockIdx.x * 8;
    int d = threadIdx.x & 127, rg = threadIdx.x >> 7;
#pragma unroll
    for (int r = 0; r < 4; ++r)
        xs[rg * 4 + r][d] = X[(row0 + rg * 4 + r) * DIMD + d];
    __syncthreads();
    float b0 = LD(Wb, offWb + d, bf);
    float a0 = b0, a1 = b0, a2 = b0, a3 = b0;
    const float* xr = &xs[rg * 4][0];
    for (int k = 0; k < DIMD; ++k) {
        float w = LD(W, offW + (long)k * DIMD + d, bf);
        a0 = fmaf(xr[0 * DIMD + k], w, a0);
        a1 = fmaf(xr[1 * DIMD + k], w, a1);
        a2 = fmaf(xr[2 * DIMD + k], w, a2);
        a3 = fmaf(xr[3 * DIMD + k], w, a3);
    }
    long ob = (row0 + rg * 4) * DIMD + d;
    hout[ob + 0 * DIMD] = a0; hs[rg * 4 + 0][d] = a0;
    hout[ob + 1 * DIMD] = a1; hs[rg * 4 + 1][d] = a1;
    hout[ob + 2 * DIMD] = a2; hs[rg * 4 + 2][d] = a2;
    hout[ob + 3 * DIMD] = a3; hs[rg * 4 + 3][d] = a3;
    __syncthreads();
    float c0 = 0.0f, c1 = 0.0f, c2 = 0.0f, c3 = 0.0f;
    const float* hr = &hs[rg * 4][0];
    for (int k = 0; k < DIMD; ++k) {
        float w = LD(A, offW + (long)k * DIMD + d, bf);
        c0 = fmaf(hr[0 * DIMD + k], w, c0);
        c1 = fmaf(hr[1 * DIMD + k], w, c1);
        c2 = fmaf(hr[2 * DIMD + k], w, c2);
        c3 = fmaf(hr[3 * DIMD + k], w, c3);
    }
    hAout[ob + 0 * DIMD] = c0;
    hAout[ob + 1 * DIMD] = c1;
    hAout[ob + 2 * DIMD] = c2;
    hAout[ob + 3 * DIMD] = c3;
}

// e[b,j,k] = hA_j . h_k + h_j . hA_k  (symmetric!). Batched GEMM, K=256.
// Upper-triangle tiles only; mirror-write the transpose into the lower tile.
// Grid x: [0,36) target tiles, [36,39) ligand tiles. 64x64 tile, 4x4 acc.
__global__ void esym_both(const float* __restrict__ hA_t, const float* __restrict__ h_t,
                          float* __restrict__ e_t,
                          const float* __restrict__ hA_l, const float* __restrict__ h_l,
                          float* __restrict__ e_l) {
    __shared__ float At[BKT][BMT + 4];
    __shared__ float Bt[BKT][BMT + 4];
    int idx = blockIdx.x, b = blockIdx.y, t = threadIdx.x;
    const float *hA, *h; float* e; int N;
    if (idx < TGT_TILES) { hA = hA_t; h = h_t; e = e_t; N = TT; }
    else { idx -= TGT_TILES; hA = hA_l; h = h_l; e = e_l; N = LL; }
    int jt = (int)((sqrtf(8.0f * idx + 1.0f) - 1.0f) * 0.5f);
    while ((jt + 1) * (jt + 2) / 2 <= idx) ++jt;
    while (jt * (jt + 1) / 2 > idx) --jt;
    int kt = idx - jt * (jt + 1) / 2;   // kt <= jt
    const float* hAb = hA + (long)b * N * DIMD;
    const float* hb  = h  + (long)b * N * DIMD;
    int tm = t & 15, tn = t >> 4;
    int k4 = (t & 7) * 4;
    int row0 = t >> 3;
    float acc[4][4];
#pragma unroll
    for (int i = 0; i < 4; ++i)
#pragma unroll
        for (int jj = 0; jj < 4; ++jj) acc[i][jj] = 0.0f;

#pragma unroll
    for (int c = 0; c < 8; ++c) {
        const float* Ap = (c < 4) ? hAb : hb;
        const float* Bp = (c < 4) ? hb : hAb;
        int ko = (c & 3) * BKT;
        __syncthreads();
#pragma unroll
        for (int rr = 0; rr < 2; ++rr) {
            int row = row0 + rr * 32;
            float4 av = *(const float4*)&Ap[(long)(jt * BMT + row) * DIMD + ko + k4];
            float4 bv = *(const float4*)&Bp[(long)(kt * BMT + row) * DIMD + ko + k4];
            At[k4 + 0][row] = av.x; At[k4 + 1][row] = av.y;
            At[k4 + 2][row] = av.z; At[k4 + 3][row] = av.w;
            Bt[k4 + 0][row] = bv.x; Bt[k4 + 1][row] = bv.y;
            Bt[k4 + 2][row] = bv.z; Bt[k4 + 3][row] = bv.w;
        }
        __syncthreads();
#pragma unroll
        for (int k = 0; k < BKT; ++k) {
            float4 a4 = *(const float4*)&At[k][tm * 4];
            float4 b4 = *(const float4*)&Bt[k][tn * 4];
            float A[4] = {a4.x, a4.y, a4.z, a4.w};
            float Bv[4] = {b4.x, b4.y, b4.z, b4.w};
#pragma unroll
            for (int i = 0; i < 4; ++i)
#pragma unroll
                for (int jj = 0; jj < 4; ++jj)
                    acc[i][jj] = fmaf(A[i], Bv[jj], acc[i][jj]);
        }
    }
    long ebN = (long)b * N;
    long ebase = (ebN + jt * BMT + tm * 4) * N + kt * BMT + tn * 4;
#pragma unroll
    for (int i = 0; i < 4; ++i) {
        float4 v;
        v.x = acc[i][0]; v.y = acc[i][1]; v.z = acc[i][2]; v.w = acc[i][3];
        *(float4*)&e[ebase + (long)i * N] = v;
    }
    if (jt != kt) {   // mirror tile (transpose), also float4-coalesced
        long mbase = (ebN + kt * BMT + tn * 4) * N + jt * BMT + tm * 4;
#pragma unroll
        for (int jj = 0; jj < 4; ++jj) {
            float4 v;
            v.x = acc[0][jj]; v.y = acc[1][jj]; v.z = acc[2][jj]; v.w = acc[3][jj];
            *(float4*)&e[mbase + (long)jj * N] = v;
        }
    }
}

// Fused softmax + hp-GEMM + gate. One block = 16 rows of one side.
// adj is exactly 0/1, so softmax(masked)*adj == softmax(masked) (masked
// entries underflow to 0): the adj multiply drops out.
// Softmax -> att in LDS [16][513]; h double-buffered [32][128] via reg
// prefetch; hp never hits global; gate updates x in place.
// Grid x: [0, TT/16) target tiles, [TT/16, TT/16+LL/16) ligand tiles.
__global__ void hp_fused_gate(const float* __restrict__ e_t, const float* __restrict__ h_t,
                              float* __restrict__ x_t, const void* __restrict__ adj_t,
                              const float* __restrict__ e_l, const float* __restrict__ h_l,
                              float* __restrict__ x_l, const void* __restrict__ adj_l,
                              const void* __restrict__ gW, long offgW,
                              const void* __restrict__ gb, long offgb,
                              const int* __restrict__ flagp) {
    __shared__ float attL[16][513];
    __shared__ float Ht[32][DIMD];
    int bf = *flagp;
    int gx = blockIdx.x, b = blockIdx.y, t = threadIdx.x;
    const float *e, *h; float* xv; const void* adj; int N, tile;
    if (gx < TT / 16) { e = e_t; h = h_t; xv = x_t; adj = adj_t; N = TT; tile = gx; }
    else { e = e_l; h = h_l; xv = x_l; adj = adj_l; N = LL; tile = gx - TT / 16; }
    int row0 = tile * 16;
    const float* hb = h + (long)b * N * DIMD;
    int tm = t & 7, tn = t >> 3;        // GEMM: rows tm*2.., cols tn*4..
    int hk = t >> 5, hc4 = (t & 31) * 4; // Ht staging
    // preload h tile 0 (hides under softmax)
    float4 pre[4];
#pragma unroll
    for (int p = 0; p < 4; ++p)
        pre[p] = *(const float4*)&hb[(long)(hk + p * 8) * DIMD + hc4];
    // softmax: wave w handles local rows w*4 .. w*4+3 (no barriers)
    int w = t >> 6, lane = t & 63;
    for (int r = 0; r < 4; ++r) {
        int lr = w * 4 + r;
        int j = row0 + lr;
        const float* erow = e + ((long)b * N + j) * N;
        long abase = ((long)b * N + j) * N;
        float* arow = attL[lr];
        float m = -3.4e38f;
        for (int k = lane; k < N; k += 64) {
            float a = LD(adj, abase + k, bf);
            float v = (a > 0.0f) ? erow[k] : -9e15f;
            arow[k] = v;
            m = fmaxf(m, v);
        }
#pragma unroll
        for (int s = 32; s > 0; s >>= 1) m = fmaxf(m, __shfl_xor(m, s));
        float sum = 0.0f;
        for (int k = lane; k < N; k += 64) {
            float v = expf(arow[k] - m);   // masked -> exactly 0
            sum += v;
            arow[k] = v;
        }
#pragma unroll
        for (int s = 32; s > 0; s >>= 1) sum += __shfl_xor(sum, s);
        float inv = 1.0f / sum;
        for (int k = lane; k < N; k += 64) arow[k] *= inv;
    }
    // hp GEMM: acc[i][j] = sum_k att[tm*2+i][k] * h[k][tn*4+j]
    float acc[2][4] = {};
    int NT = N / 32;
    for (int kt = 0; kt < NT; ++kt) {
        __syncthreads();   // first iter: softmax done; later: Ht consumed
#pragma unroll
        for (int p = 0; p < 4; ++p) *(float4*)&Ht[hk + p * 8][hc4] = pre[p];
        if (kt + 1 < NT) {
#pragma unroll
            for (int p = 0; p < 4; ++p)
                pre[p] = *(const float4*)&hb[(long)((kt + 1) * 32 + hk + p * 8) * DIMD + hc4];
        }
        __syncthreads();
#pragma unroll
        for (int k = 0; k < 32; ++k) {
            float a0 = attL[tm * 2 + 0][kt * 32 + k];
            float a1 = attL[tm * 2 + 1][kt * 32 + k];
            float4 h4 = *(const float4*)&Ht[k][tn * 4];
            acc[0][0] = fmaf(a0, h4.x, acc[0][0]);
            acc[0][1] = fmaf(a0, h4.y, acc[0][1]);
            acc[0][2] = fmaf(a0, h4.z, acc[0][2]);
            acc[0][3] = fmaf(a0, h4.w, acc[0][3]);
            acc[1][0] = fmaf(a1, h4.x, acc[1][0]);
            acc[1][1] = fmaf(a1, h4.y, acc[1][1]);
            acc[1][2] = fmaf(a1, h4.z, acc[1][2]);
            acc[1][3] = fmaf(a1, h4.w, acc[1][3]);
        }
    }
    // gate: stash hp=relu(acc) into attL cols [0,128), then per-row reduce
    __syncthreads();
#pragma unroll
    for (int i = 0; i < 2; ++i)
#pragma unroll
        for (int jj = 0; jj < 4; ++jj)
            attL[tm * 2 + i][tn * 4 + jj] = fmaxf(acc[i][jj], 0.0f);
    __syncthreads();
    for (int r = 0; r < 4; ++r) {
        int lr = w * 4 + r;
        int j = row0 + lr;
        float* xrow = xv + ((long)b * N + j) * DIMD;
        float x0 = xrow[lane], x1 = xrow[lane + 64];
        float hp0 = attL[lr][lane], hp1 = attL[lr][lane + 64];
        float g = x0 * LD(gW, offgW + lane, bf) + x1 * LD(gW, offgW + lane + 64, bf)
                + hp0 * LD(gW, offgW + DIMD + lane, bf)
                + hp1 * LD(gW, offgW + DIMD + lane + 64, bf);
#pragma unroll
        for (int s = 32; s > 0; s >>= 1) g += __shfl_xor(g, s);
        g += LD(gb, offgb, bf);
        float coeff = 1.0f / (1.0f + expf(-g));
        xrow[lane] = coeff * x0 + (1.0f - coeff) * hp0;
        xrow[lane + 64] = coeff * x1 + (1.0f - coeff) * hp1;
    }
}

// Both pair-MLP projections in one launch. blockIdx.y: 0=dc set, 1=vdwA set.
// Rows < rowsplit (ligand) use W1[:D] + b1; rest (target) use W1[D:], no bias.
// 8 rows/block, 256 threads.
__global__ void proj_both(const float* __restrict__ X,
                          const void* __restrict__ Wdc, const void* __restrict__ bdc,
                          const void* __restrict__ WA, const void* __restrict__ bA,
                          long rowsplit, float* __restrict__ outdc, float* __restrict__ outA,
                          const int* __restrict__ flagp) {
    __shared__ float xs[8][DIMD];
    int bf = *flagp;
    const void* W; const void* bias; float* out;
    if (blockIdx.y == 0) { W = Wdc; bias = bdc; out = outdc; }
    else                 { W = WA;  bias = bA;  out = outA; }
    long row0 = (long)blockIdx.x * 8;
    int d = threadIdx.x & 127, rg = threadIdx.x >> 7;
    int sideb = row0 >= rowsplit;
    long offW = sideb ? (long)DIMD * DIMD : 0;
    int hasb = !sideb;
#pragma unroll
    for (int r = 0; r < 4; ++r)
        xs[rg * 4 + r][d] = X[(row0 + rg * 4 + r) * DIMD + d];
    __syncthreads();
    float b0 = hasb ? LD(bias, d, bf) : 0.0f;
    float a0 = b0, a1 = b0, a2 = b0, a3 = b0;
    const float* xr = &xs[rg * 4][0];
    for (int k = 0; k < DIMD; ++k) {
        float w = LD(W, offW + (long)k * DIMD + d, bf);
        a0 = fmaf(xr[0 * DIMD + k], w, a0);
        a1 = fmaf(xr[1 * DIMD + k], w, a1);
        a2 = fmaf(xr[2 * DIMD + k], w, a2);
        a3 = fmaf(xr[3 * DIMD + k], w, a3);
    }
    long ob = (row0 + rg * 4) * DIMD + d;
    out[ob + 0 * DIMD] = a0;
    out[ob + 1 * DIMD] = a1;
    out[ob + 2 * DIMD] = a2;
    out[ob + 3 * DIMD] = a3;
}

// Both transposes in one launch: z<BB -> (in0->out0, b=z), else (in1->out1).
__global__ void transpose_both(const float* __restrict__ in0, float* __restrict__ out0,
                               const float* __restrict__ in1, float* __restrict__ out1) {
    __shared__ float tile[32][33];
    int z = blockIdx.z;
    const float* in; float* outT; int b;
    if (z < BB) { in = in0; outT = out0; b = z; }
    else        { in = in1; outT = out1; b = z - BB; }
    int n0 = blockIdx.x * 32;
    int d0 = blockIdx.y * 32;
    int t = threadIdx.x;
    int tx = t & 31, ty = t >> 5;
    for (int r = ty; r < 32; r += 8)
        tile[r][tx] = in[((long)b * TT + n0 + r) * DIMD + d0 + tx];
    __syncthreads();
    for (int r = ty; r < 32; r += 8)
        outT[((long)b * DIMD + d0 + r) * TT + n0 + tx] = tile[tx][r];
}

// Pair energies. Block = (b, 2 ligand rows). Lane handles tt = 2t, 2t+1.
__global__ void pair_energy(const float* __restrict__ ligdc, const float* __restrict__ tgtdcT,
                            const float* __restrict__ ligA, const float* __restrict__ tgtAT,
                            const void* __restrict__ dcW2, const void* __restrict__ dcb2,
                            const void* __restrict__ AW2, const void* __restrict__ Ab2,
                            const void* __restrict__ lpos, const void* __restrict__ tpos,
                            const void* __restrict__ lrad, const void* __restrict__ trad,
                            const void* __restrict__ lval, const void* __restrict__ tval,
                            const void* __restrict__ ii, float* __restrict__ accum,
                            const int* __restrict__ flagp) {
    int bf = *flagp;
    int l0 = blockIdx.x * 2, b = blockIdx.y, t = threadIdx.x;
    __shared__ __align__(16) float sdc0[DIMD], sdc1[DIMD], sA0[DIMD], sA1[DIMD];
    __shared__ __align__(16) float w2dc[DIMD], w2A[DIMD];
    __shared__ float red[256];
    if (t < DIMD) {
        sdc0[t] = ligdc[((long)b * LL + l0) * DIMD + t];
        sA0[t]  = ligA [((long)b * LL + l0) * DIMD + t];
        w2dc[t] = LD(dcW2, t, bf);
        w2A[t]  = LD(AW2, t, bf);
    } else {
        int u = t - DIMD;
        sdc1[u] = ligdc[((long)b * LL + l0 + 1) * DIMD + u];
        sA1[u]  = ligA [((long)b * LL + l0 + 1) * DIMD + u];
    }
    __syncthreads();
    int tt0 = t * 2;
    const float* tdT = tgtdcT + (long)b * DIMD * TT;
    const float* taT = tgtAT  + (long)b * DIMD * TT;
    float adc00 = 0.0f, adc01 = 0.0f, adc10 = 0.0f, adc11 = 0.0f;
    float aA00 = 0.0f, aA01 = 0.0f, aA10 = 0.0f, aA11 = 0.0f;
    for (int i4 = 0; i4 < DIMD; i4 += 4) {
        float4 wd = *(const float4*)&w2dc[i4];
        float4 wa = *(const float4*)&w2A[i4];
        float4 v0d = *(const float4*)&sdc0[i4];
        float4 v1d = *(const float4*)&sdc1[i4];
        float4 v0a = *(const float4*)&sA0[i4];
        float4 v1a = *(const float4*)&sA1[i4];
        float wdv[4] = {wd.x, wd.y, wd.z, wd.w};
        float wav[4] = {wa.x, wa.y, wa.z, wa.w};
        float s0d[4] = {v0d.x, v0d.y, v0d.z, v0d.w};
        float s1d[4] = {v1d.x, v1d.y, v1d.z, v1d.w};
        float s0a[4] = {v0a.x, v0a.y, v0a.z, v0a.w};
        float s1a[4] = {v1a.x, v1a.y, v1a.z, v1a.w};
#pragma unroll
        for (int j = 0; j < 4; ++j) {
            float2 td = *(const float2*)&tdT[(long)(i4 + j) * TT + tt0];
            float2 ta = *(const float2*)&taT[(long)(i4 + j) * TT + tt0];
            adc00 = fmaf(fmaxf(td.x + s0d[j], 0.0f), wdv[j], adc00);
            adc01 = fmaf(fmaxf(td.y + s0d[j], 0.0f), wdv[j], adc01);
            adc10 = fmaf(fmaxf(td.x + s1d[j], 0.0f), wdv[j], adc10);
            adc11 = fmaf(fmaxf(td.y + s1d[j], 0.0f), wdv[j], adc11);
            aA00 = fmaf(fmaxf(ta.x + s0a[j], 0.0f), wav[j], aA00);
            aA01 = fmaf(fmaxf(ta.y + s0a[j], 0.0f), wav[j], aA01);
            aA10 = fmaf(fmaxf(ta.x + s1a[j], 0.0f), wav[j], aA10);
            aA11 = fmaf(fmaxf(ta.y + s1a[j], 0.0f), wav[j], aA11);
        }
    }
    float lx0 = LD(lpos, ((long)b * LL + l0) * 3 + 0, bf);
    float ly0 = LD(lpos, ((long)b * LL + l0) * 3 + 1, bf);
    float lz0 = LD(lpos, ((long)b * LL + l0) * 3 + 2, bf);
    float lx1 = LD(lpos, ((long)b * LL + l0 + 1) * 3 + 0, bf);
    float ly1 = LD(lpos, ((long)b * LL + l0 + 1) * 3 + 1, bf);
    float lz1 = LD(lpos, ((long)b * LL + l0 + 1) * 3 + 2, bf);
    float lr0 = LD(lrad, (long)b * LL + l0, bf);
    float lr1 = LD(lrad, (long)b * LL + l0 + 1, bf);
    float lv0 = LD(lval, (long)b * LL + l0, bf);
    float lv1 = LD(lval, (long)b * LL + l0 + 1, bf);
    float cdcb2 = LD(dcb2, 0, bf), cab2 = LD(Ab2, 0, bf);
    long iiA0 = ((long)(b * 3 + 0) * LL + l0) * TT;
    long iiB0 = ((long)(b * 3 + 1) * LL + l0) * TT;
    long iiC0 = ((long)(b * 3 + 2) * LL + l0) * TT;
    long iiA1 = iiA0 + TT, iiB1 = iiB0 + TT, iiC1 = iiC0 + TT;
    float p0 = 0.0f, p1 = 0.0f, p2 = 0.0f, p3 = 0.0f;
#pragma unroll
    for (int jj = 0; jj < 2; ++jj) {
        int tt = tt0 + jj;
        float tx = LD(tpos, ((long)b * TT + tt) * 3 + 0, bf);
        float ty = LD(tpos, ((long)b * TT + tt) * 3 + 1, bf);
        float tz = LD(tpos, ((long)b * TT + tt) * 3 + 2, bf);
        float tr = LD(trad, (long)b * TT + tt, bf);
        float tv = LD(tval, (long)b * TT + tt, bf);
#pragma unroll
        for (int li = 0; li < 2; ++li) {
            float dx = (li ? lx1 : lx0) - tx;
            float dy = (li ? ly1 : ly0) - ty;
            float dz = (li ? lz1 : lz0) - tz;
            float dm = sqrtf(dx * dx + dy * dy + dz * dz + 1e-10f);
            if (dm < 0.5f) dm = 1e10f;
            float adcv = jj ? (li ? adc11 : adc01) : (li ? adc10 : adc00);
            float aAv  = jj ? (li ? aA11  : aA01)  : (li ? aA10  : aA00);
            float dev = tanhf(adcv + cdcb2) * 0.2f;
            float vdws = (li ? lr1 : lr0) + tr + dev;
            float dm0 = (vdws < 1e-4f) ? 1.0f : vdws;
            float ratio = dm0 / dm;
            float r2 = ratio * ratio, r6 = r2 * r2 * r2, r12 = r6 * r6;
            float en = fminf(r12 - 2.0f * r6, 100.0f) * (li ? lv1 : lv0) * tv;
            float As = 1.0f / (1.0f + expf(-(aAv + cab2)));
            As = As * (0.0356f - 0.0178f) + 0.0178f;
            p0 = fmaf(As, en, p0);
            float dd = dm - vdws;
            float ramp = fminf(fmaxf(dd * (1.0f / -0.7f), 0.0f), 1.0f);
            p1 = fmaf(ramp, LD(ii, (li ? iiA1 : iiA0) + tt, bf), p1);
            p2 = fmaf(ramp, LD(ii, (li ? iiB1 : iiB0) + tt, bf), p2);
            float ramp2 = fminf(fmaxf(-dd + 1.5f, 0.0f), 1.0f);
            p3 = fmaf(ramp2, LD(ii, (li ? iiC1 : iiC0) + tt, bf), p3);
        }
    }
    for (int e = 0; e < 4; ++e) {
        float v = (e == 0) ? p0 : (e == 1) ? p1 : (e == 2) ? p2 : p3;
        red[t] = v; __syncthreads();
        for (int s = 128; s > 0; s >>= 1) { if (t < s) red[t] += red[t + s]; __syncthreads(); }
        if (t == 0) atomicAdd(&accum[b * 4 + e], red[0]);
        __syncthreads();
    }
}

__global__ void finalize(const float* __restrict__ accum, const void* __restrict__ hb,
                         const void* __restrict__ mc, const void* __restrict__ hyd,
                         const void* __restrict__ rc, const void* __restrict__ rotor,
                         void* __restrict__ out, const int* __restrict__ flagp) {
    int bf = *flagp;
    int t = threadIdx.x;  // 64 threads, use first 32
    if (t >= 32) return;
    int b = t >> 2, e = t & 3;
    float v = accum[t];
    if (e == 1) { float c = LD(hb, 0, bf);  v = -c * c * v; }
    else if (e == 2) { float c = LD(mc, 0, bf);  v = -c * c * v; }
    else if (e == 3) { float c = LD(hyd, 0, bf); v = -c * c * v; }
    float r = LD(rc, 0, bf);
    float den = 1.0f + r * r * LD(rotor, b, bf);
    float res = v / den;
    if (bf) ((bf16*)out)[t] = __float2bfloat16(res);
    else    ((float*)out)[t] = res;
}

extern "C" void kernel_launch(void* const* d_in, const int* in_sizes, int n_in,
                              void* d_out, int out_size, void* d_ws, size_t ws_size,
                              hipStream_t stream) {
    const void* ligand_h = d_in[0];
    const void* target_h = d_in[1];
    const void* ligand_adj = d_in[2];
    const void* target_adj = d_in[3];
    const void* interaction_indice = d_in[4];
    const void* ligand_pos = d_in[5];
    const void* target_pos = d_in[6];
    const void* rotor = d_in[7];
    const void* ligand_vdw = d_in[8];
    const void* target_vdw = d_in[9];
    const void* ligand_valid = d_in[10];
    const void* target_valid = d_in[11];
    const void* emb_W = d_in[12];
    const void* gat_W = d_in[13];
    const void* gat_Wb = d_in[14];
    const void* gat_A = d_in[15];
    const void* gat_gW = d_in[16];
    const void* gat_gb = d_in[17];
    const void* vdwA_W1 = d_in[18];
    const void* vdwA_b1 = d_in[19];
    const void* vdwA_W2 = d_in[20];
    const void* vdwA_b2 = d_in[21];
    const void* dc_W1 = d_in[22];
    const void* dc_b1 = d_in[23];
    const void* dc_W2 = d_in[24];
    const void* dc_b2 = d_in[25];
    const void* hbond_coeff = d_in[26];
    const void* metal_coeff = d_in[27];
    const void* hydrophobic_coeff = d_in[28];
    const void* rotor_coeff = d_in[29];

    float* ws = (float*)d_ws;
    size_t off = 0;
    float* lig_x = ws + off;  off += (size_t)BB * LL * DIMD;   // contiguous with tgt_x
    float* tgt_x = ws + off;  off += (size_t)BB * TT * DIMD;
    float* h_lig = ws + off;  off += (size_t)BB * LL * DIMD;   // contiguous with h_tgt
    float* h_tgt = ws + off;  off += (size_t)BB * TT * DIMD;
    float* hA_lig = ws + off; off += (size_t)BB * LL * DIMD;   // contiguous with hA_tgt
    float* hA_tgt = ws + off; off += (size_t)BB * TT * DIMD;
    float* accum = ws + off;  off += 32;
    int* flagp = (int*)(ws + off); off += 2;
    float* e_buf = ws + off;  off += (size_t)BB * TT * TT;     // 8MB target e; reused for transposes
    float* e_lig = ws + off;  off += (size_t)BB * LL * LL;     // 512KB ligand e
    // pair-MLP projections reuse h/hA buffers (dead after the GAT loop)
    float* ligdc = h_lig;    // merged out base (rows: lig then tgt)
    float* ligA = hA_lig;
    float* tgtdc = h_tgt;
    float* tgtA  = hA_tgt;
    // transposed target projections reuse e_buf (dead after the GAT loop)
    float* tgtdcT = e_buf;
    float* tgtAT  = e_buf + (size_t)BB * DIMD * TT;

    init_ws<<<1, 64, 0, stream>>>((const unsigned int*)emb_W, accum, flagp);

    // embeddings: x = h @ emb_W (both sides, one launch; out rows contiguous)
    embed_both<<<BB * (LL + TT), DIMD, 0, stream>>>(ligand_h, target_h, emb_W, lig_x, 54, flagp);

    const long ROWSPLIT = (long)BB * LL;   // multiple of 8
    for (int i = 0; i < 3; ++i) {
        long offW = (long)i * DIMD * DIMD;
        long offWb = (long)i * DIMD;
        long offgW = (long)i * 2 * DIMD;
        long offgb = i;
        // h = x@W + Wb ; hA = h@A  (both sides, one launch — shared weights)
        gemm_hha<<<BB * (LL + TT) / 8, 256, 0, stream>>>(
            lig_x, gat_W, gat_A, offW, gat_Wb, offWb, h_lig, hA_lig, flagp);
        // e (symmetric, upper tiles + mirror), both sides
        esym_both<<<dim3(TGT_TILES + LIG_TILES, BB), 256, 0, stream>>>(
            hA_tgt, h_tgt, e_buf, hA_lig, h_lig, e_lig);
        // softmax + hp GEMM + gate, fused; both sides
        hp_fused_gate<<<dim3(TT / 16 + LL / 16, BB), 256, 0, stream>>>(
            e_buf, h_tgt, tgt_x, target_adj, e_lig, h_lig, lig_x, ligand_adj,
            gat_gW, offgW, gat_gb, offgb, flagp);
    }

    // pair-MLP projections, both weight sets in one launch
    proj_both<<<dim3(BB * (LL + TT) / 8, 2), 256, 0, stream>>>(
        lig_x, dc_W1, dc_b1, vdwA_W1, vdwA_b1, ROWSPLIT, ligdc, ligA, flagp);

    // transpose target projections for coalesced pair_energy reads (one launch)
    transpose_both<<<dim3(TT / 32, DIMD / 32, 2 * BB), 256, 0, stream>>>(
        tgtdc, tgtdcT, tgtA, tgtAT);

    pair_energy<<<dim3(LL / 2, BB), 256, 0, stream>>>(
        ligdc, tgtdcT, ligA, tgtAT, dc_W2, dc_b2, vdwA_W2, vdwA_b2,
        ligand_pos, target_pos, ligand_vdw, target_vdw,
        ligand_valid, target_valid, interaction_indice, accum, flagp);

    finalize<<<1, 64, 0, stream>>>(accum, hbond_coeff, metal_coeff,
                                   hydrophobic_coeff, rotor_coeff, rotor, d_out, flagp);
}

// Round 6
// 439.013 us; speedup vs baseline: 1.2604x; 1.2604x over previous
//
#include <hip/hip_runtime.h>
#include <hip/hip_bf16.h>
#include <math.h>

typedef __hip_bfloat16 bf16;

#define DIMD 128
#define BB 8
#define LL 128
#define TT 512

// esym tile params
#define BMT 64
#define BKT 32
#define TGT_TILES 36   // 8*9/2 upper-tri tiles (N=512 / 64)
#define LIG_TILES 3    // 2*3/2 upper-tri tiles (N=128 / 64)

// Runtime-dtype load of external inputs: bf==1 -> bf16, else f32.
__device__ __forceinline__ float LD(const void* p, long i, int bf) {
    if (bf) return __bfloat162float(((const bf16*)p)[i]);
    return ((const float*)p)[i];
}

// Detect external dtype from emb_W bit patterns + zero the accumulators.
__global__ void init_ws(const unsigned int* __restrict__ embw_raw,
                        float* __restrict__ accum, int* __restrict__ flagp) {
    int t = threadIdx.x;
    if (t < 32) accum[t] = 0.0f;
    if (t == 0) {
        int cnt = 0;
        for (int k = 0; k < 256; ++k) {
            unsigned int b = (embw_raw[k] >> 8) & 0xffu;
            unsigned int e = b & 0x7fu;
            if (e >= 0x38u && e <= 0x3fu) ++cnt;
        }
        *flagp = (cnt > 128) ? 1 : 0;
    }
}

// Both-sides embedding: rows [0, BB*LL) from Xl, rest from Xt. K=54.
__global__ void embed_both(const void* __restrict__ Xl, const void* __restrict__ Xt,
                           const void* __restrict__ W, float* __restrict__ out,
                           int K, const int* __restrict__ flagp) {
    __shared__ float xrow[DIMD];
    int bf = *flagp;
    int row = blockIdx.x;
    int d = threadIdx.x;
    const void* X; long r;
    if (row < BB * LL) { X = Xl; r = row; }
    else               { X = Xt; r = row - BB * LL; }
    if (d < K) xrow[d] = LD(X, r * K + d, bf);
    __syncthreads();
    float acc = 0.0f;
    for (int k = 0; k < K; ++k)
        acc = fmaf(xrow[k], LD(W, (long)k * DIMD + d, bf), acc);
    out[(long)row * DIMD + d] = acc;
}

// Fused h = x@W + Wb  and  hA = h@A  (row-local chain; h staged in LDS).
// 8 rows/block, 256 threads (2 row-groups x 128 cols). Same weights both sides.
__global__ void gemm_hha(const float* __restrict__ X, const void* __restrict__ W,
                         const void* __restrict__ A, long offW,
                         const void* __restrict__ Wb, long offWb,
                         float* __restrict__ hout, float* __restrict__ hAout,
                         const int* __restrict__ flagp) {
    __shared__ float xs[8][DIMD];
    __shared__ float hs[8][DIMD];
    int bf = *flagp;
    long row0 = (long)blockIdx.x * 8;
    int d = threadIdx.x & 127, rg = threadIdx.x >> 7;
#pragma unroll
    for (int r = 0; r < 4; ++r)
        xs[rg * 4 + r][d] = X[(row0 + rg * 4 + r) * DIMD + d];
    __syncthreads();
    float b0 = LD(Wb, offWb + d, bf);
    float a0 = b0, a1 = b0, a2 = b0, a3 = b0;
    const float* xr = &xs[rg * 4][0];
    for (int k = 0; k < DIMD; ++k) {
        float w = LD(W, offW + (long)k * DIMD + d, bf);
        a0 = fmaf(xr[0 * DIMD + k], w, a0);
        a1 = fmaf(xr[1 * DIMD + k], w, a1);
        a2 = fmaf(xr[2 * DIMD + k], w, a2);
        a3 = fmaf(xr[3 * DIMD + k], w, a3);
    }
    long ob = (row0 + rg * 4) * DIMD + d;
    hout[ob + 0 * DIMD] = a0; hs[rg * 4 + 0][d] = a0;
    hout[ob + 1 * DIMD] = a1; hs[rg * 4 + 1][d] = a1;
    hout[ob + 2 * DIMD] = a2; hs[rg * 4 + 2][d] = a2;
    hout[ob + 3 * DIMD] = a3; hs[rg * 4 + 3][d] = a3;
    __syncthreads();
    float c0 = 0.0f, c1 = 0.0f, c2 = 0.0f, c3 = 0.0f;
    const float* hr = &hs[rg * 4][0];
    for (int k = 0; k < DIMD; ++k) {
        float w = LD(A, offW + (long)k * DIMD + d, bf);
        c0 = fmaf(hr[0 * DIMD + k], w, c0);
        c1 = fmaf(hr[1 * DIMD + k], w, c1);
        c2 = fmaf(hr[2 * DIMD + k], w, c2);
        c3 = fmaf(hr[3 * DIMD + k], w, c3);
    }
    hAout[ob + 0 * DIMD] = c0;
    hAout[ob + 1 * DIMD] = c1;
    hAout[ob + 2 * DIMD] = c2;
    hAout[ob + 3 * DIMD] = c3;
}

// e[b,j,k] = hA_j . h_k + h_j . hA_k  (symmetric!). Batched GEMM, K=256.
// Upper-triangle tiles only; mirror-write the transpose into the lower tile.
// Grid x: [0,36) target tiles, [36,39) ligand tiles. 64x64 tile, 4x4 acc.
__global__ void esym_both(const float* __restrict__ hA_t, const float* __restrict__ h_t,
                          float* __restrict__ e_t,
                          const float* __restrict__ hA_l, const float* __restrict__ h_l,
                          float* __restrict__ e_l) {
    __shared__ float At[BKT][BMT + 4];
    __shared__ float Bt[BKT][BMT + 4];
    int idx = blockIdx.x, b = blockIdx.y, t = threadIdx.x;
    const float *hA, *h; float* e; int N;
    if (idx < TGT_TILES) { hA = hA_t; h = h_t; e = e_t; N = TT; }
    else { idx -= TGT_TILES; hA = hA_l; h = h_l; e = e_l; N = LL; }
    int jt = (int)((sqrtf(8.0f * idx + 1.0f) - 1.0f) * 0.5f);
    while ((jt + 1) * (jt + 2) / 2 <= idx) ++jt;
    while (jt * (jt + 1) / 2 > idx) --jt;
    int kt = idx - jt * (jt + 1) / 2;   // kt <= jt
    const float* hAb = hA + (long)b * N * DIMD;
    const float* hb  = h  + (long)b * N * DIMD;
    int tm = t & 15, tn = t >> 4;
    int k4 = (t & 7) * 4;
    int row0 = t >> 3;
    float acc[4][4];
#pragma unroll
    for (int i = 0; i < 4; ++i)
#pragma unroll
        for (int jj = 0; jj < 4; ++jj) acc[i][jj] = 0.0f;

#pragma unroll
    for (int c = 0; c < 8; ++c) {
        const float* Ap = (c < 4) ? hAb : hb;
        const float* Bp = (c < 4) ? hb : hAb;
        int ko = (c & 3) * BKT;
        __syncthreads();
#pragma unroll
        for (int rr = 0; rr < 2; ++rr) {
            int row = row0 + rr * 32;
            float4 av = *(const float4*)&Ap[(long)(jt * BMT + row) * DIMD + ko + k4];
            float4 bv = *(const float4*)&Bp[(long)(kt * BMT + row) * DIMD + ko + k4];
            At[k4 + 0][row] = av.x; At[k4 + 1][row] = av.y;
            At[k4 + 2][row] = av.z; At[k4 + 3][row] = av.w;
            Bt[k4 + 0][row] = bv.x; Bt[k4 + 1][row] = bv.y;
            Bt[k4 + 2][row] = bv.z; Bt[k4 + 3][row] = bv.w;
        }
        __syncthreads();
#pragma unroll
        for (int k = 0; k < BKT; ++k) {
            float4 a4 = *(const float4*)&At[k][tm * 4];
            float4 b4 = *(const float4*)&Bt[k][tn * 4];
            float A[4] = {a4.x, a4.y, a4.z, a4.w};
            float Bv[4] = {b4.x, b4.y, b4.z, b4.w};
#pragma unroll
            for (int i = 0; i < 4; ++i)
#pragma unroll
                for (int jj = 0; jj < 4; ++jj)
                    acc[i][jj] = fmaf(A[i], Bv[jj], acc[i][jj]);
        }
    }
    long ebN = (long)b * N;
    long ebase = (ebN + jt * BMT + tm * 4) * N + kt * BMT + tn * 4;
#pragma unroll
    for (int i = 0; i < 4; ++i) {
        float4 v;
        v.x = acc[i][0]; v.y = acc[i][1]; v.z = acc[i][2]; v.w = acc[i][3];
        *(float4*)&e[ebase + (long)i * N] = v;
    }
    if (jt != kt) {   // mirror tile (transpose), also float4-coalesced
        long mbase = (ebN + kt * BMT + tn * 4) * N + jt * BMT + tm * 4;
#pragma unroll
        for (int jj = 0; jj < 4; ++jj) {
            float4 v;
            v.x = acc[0][jj]; v.y = acc[1][jj]; v.z = acc[2][jj]; v.w = acc[3][jj];
            *(float4*)&e[mbase + (long)jj * N] = v;
        }
    }
}

// att row softmax, one WAVE per row (no barriers). In-place on e.
template<int CNT>
__device__ __forceinline__ void softmax_row(float* __restrict__ erow,
                                            const void* __restrict__ adj,
                                            long adjbase, int bf) {
    int lane = threadIdx.x & 63;
    float vals[CNT], av[CNT];
    float m = -3.4e38f;
#pragma unroll
    for (int i = 0; i < CNT; ++i) {
        int k = lane + i * 64;
        float a = LD(adj, adjbase + k, bf);
        float v = (a > 0.0f) ? erow[k] : -9e15f;
        av[i] = a; vals[i] = v;
        m = fmaxf(m, v);
    }
#pragma unroll
    for (int s = 32; s > 0; s >>= 1) m = fmaxf(m, __shfl_xor(m, s));
    float sum = 0.0f;
#pragma unroll
    for (int i = 0; i < CNT; ++i) { vals[i] = expf(vals[i] - m); sum += vals[i]; }
#pragma unroll
    for (int s = 32; s > 0; s >>= 1) sum += __shfl_xor(sum, s);
    float inv = 1.0f / sum;
#pragma unroll
    for (int i = 0; i < CNT; ++i)
        erow[lane + i * 64] = vals[i] * av[i] * inv;
}

// x < TT/4: target rows; else ligand rows. 4 waves = 4 rows per block.
__global__ void att_softmax_both(float* __restrict__ e_t, float* __restrict__ e_l,
                                 const void* __restrict__ adj_t, const void* __restrict__ adj_l,
                                 const int* __restrict__ flagp) {
    int bf = *flagp;
    int b = blockIdx.y, x = blockIdx.x;
    int jr = threadIdx.x >> 6;
    if (x < TT / 4) {
        int j = x * 4 + jr;
        long base = ((long)b * TT + j) * TT;
        softmax_row<8>(e_t + base, adj_t, base, bf);
    } else {
        int j = (x - TT / 4) * 4 + jr;
        long base = ((long)b * LL + j) * LL;
        softmax_row<2>(e_l + base, adj_l, base, bf);
    }
}

// Partial hp GEMM: part[b][j][d] = sum over k-chunk of att[b][j][k]*h[b][k][d]
// BM=32, BN=128, BK=32, 256 threads, 4x4 acc, split-K=2 via blockIdx.y.
// Grid x: [0,16) target row-tiles, [16,20) ligand row-tiles.
__global__ void hp_gemm_both(const float* __restrict__ att_t, const float* __restrict__ h_t,
                             float* __restrict__ p0_t, float* __restrict__ p1_t,
                             const float* __restrict__ att_l, const float* __restrict__ h_l,
                             float* __restrict__ p0_l, float* __restrict__ p1_l) {
    __shared__ float At[32][36];
    __shared__ float Ht[32][DIMD];
    int jt = blockIdx.x, kc = blockIdx.y, b = blockIdx.z;
    int t = threadIdx.x;
    const float *att, *h; float *part0, *part1; int N;
    if (jt < 16) { att = att_t; h = h_t; part0 = p0_t; part1 = p1_t; N = TT; }
    else { jt -= 16; att = att_l; h = h_l; part0 = p0_l; part1 = p1_l; N = LL; }
    const float* attb = att + (long)b * N * N;
    const float* hb = h + (long)b * N * DIMD;
    int tm = t & 7, tn = t >> 3;
    float acc[4][4] = {};
    int kchunk = N / 2;
    int kbeg = kc * kchunk;
    int ar = t >> 3;
    int ac4 = (t & 7) * 4;
    int hk = t >> 5;
    int hc4 = (t & 31) * 4;
    for (int k0 = kbeg; k0 < kbeg + kchunk; k0 += 32) {
        __syncthreads();
        float4 av = *(const float4*)&attb[(long)(jt * 32 + ar) * N + k0 + ac4];
        At[ac4 + 0][ar] = av.x; At[ac4 + 1][ar] = av.y;
        At[ac4 + 2][ar] = av.z; At[ac4 + 3][ar] = av.w;
#pragma unroll
        for (int p = 0; p < 4; ++p)
            *(float4*)&Ht[hk + p * 8][hc4] = *(const float4*)&hb[(long)(k0 + hk + p * 8) * DIMD + hc4];
        __syncthreads();
#pragma unroll
        for (int k = 0; k < 32; ++k) {
            float4 a4 = *(const float4*)&At[k][tm * 4];
            float4 h4 = *(const float4*)&Ht[k][tn * 4];
            float A[4] = {a4.x, a4.y, a4.z, a4.w};
            float H[4] = {h4.x, h4.y, h4.z, h4.w};
#pragma unroll
            for (int i = 0; i < 4; ++i)
#pragma unroll
                for (int jj = 0; jj < 4; ++jj)
                    acc[i][jj] = fmaf(A[i], H[jj], acc[i][jj]);
        }
    }
    float* outp = (kc == 0) ? part0 : part1;
    long obase = ((long)b * N + jt * 32 + tm * 4) * DIMD + tn * 4;
#pragma unroll
    for (int i = 0; i < 4; ++i) {
        float4 v; v.x = acc[i][0]; v.y = acc[i][1]; v.z = acc[i][2]; v.w = acc[i][3];
        *(float4*)&outp[obase + (long)i * DIMD] = v;
    }
}

// Gate: hp = relu(part0+part1); coeff = sigmoid(concat(x,hp)@gW+gb); x updated.
// One WAVE per row; x < TT/4 -> target rows, else ligand.
__global__ void gat_gate_both(float* __restrict__ x_t, float* __restrict__ x_l,
                              const float* __restrict__ p0_t, const float* __restrict__ p1_t,
                              const float* __restrict__ p0_l, const float* __restrict__ p1_l,
                              const void* __restrict__ gW, long offgW,
                              const void* __restrict__ gb, long offgb,
                              const int* __restrict__ flagp) {
    int bf = *flagp;
    int b = blockIdx.y, x = blockIdx.x;
    int jr = threadIdx.x >> 6, lane = threadIdx.x & 63;
    float* xb; const float *part0, *part1; long rbase;
    if (x < TT / 4) {
        int j = x * 4 + jr;
        rbase = ((long)b * TT + j) * DIMD;
        xb = x_t; part0 = p0_t; part1 = p1_t;
    } else {
        int j = (x - TT / 4) * 4 + jr;
        rbase = ((long)b * LL + j) * DIMD;
        xb = x_l; part0 = p0_l; part1 = p1_l;
    }
    float* xrow = xb + rbase;
    float hp0 = fmaxf(part0[rbase + lane] + part1[rbase + lane], 0.0f);
    float hp1 = fmaxf(part0[rbase + lane + 64] + part1[rbase + lane + 64], 0.0f);
    float x0 = xrow[lane], x1 = xrow[lane + 64];
    float g = x0 * LD(gW, offgW + lane, bf) + x1 * LD(gW, offgW + lane + 64, bf)
            + hp0 * LD(gW, offgW + DIMD + lane, bf) + hp1 * LD(gW, offgW + DIMD + lane + 64, bf);
#pragma unroll
    for (int s = 32; s > 0; s >>= 1) g += __shfl_xor(g, s);
    g += LD(gb, offgb, bf);
    float coeff = 1.0f / (1.0f + expf(-g));
    xrow[lane] = coeff * x0 + (1.0f - coeff) * hp0;
    xrow[lane + 64] = coeff * x1 + (1.0f - coeff) * hp1;
}

// Both pair-MLP projections in one launch. blockIdx.y: 0=dc set, 1=vdwA set.
// Rows < rowsplit (ligand) use W1[:D] + b1; rest (target) use W1[D:], no bias.
// 8 rows/block, 256 threads.
__global__ void proj_both(const float* __restrict__ X,
                          const void* __restrict__ Wdc, const void* __restrict__ bdc,
                          const void* __restrict__ WA, const void* __restrict__ bA,
                          long rowsplit, float* __restrict__ outdc, float* __restrict__ outA,
                          const int* __restrict__ flagp) {
    __shared__ float xs[8][DIMD];
    int bf = *flagp;
    const void* W; const void* bias; float* out;
    if (blockIdx.y == 0) { W = Wdc; bias = bdc; out = outdc; }
    else                 { W = WA;  bias = bA;  out = outA; }
    long row0 = (long)blockIdx.x * 8;
    int d = threadIdx.x & 127, rg = threadIdx.x >> 7;
    int sideb = row0 >= rowsplit;
    long offW = sideb ? (long)DIMD * DIMD : 0;
    int hasb = !sideb;
#pragma unroll
    for (int r = 0; r < 4; ++r)
        xs[rg * 4 + r][d] = X[(row0 + rg * 4 + r) * DIMD + d];
    __syncthreads();
    float b0 = hasb ? LD(bias, d, bf) : 0.0f;
    float a0 = b0, a1 = b0, a2 = b0, a3 = b0;
    const float* xr = &xs[rg * 4][0];
    for (int k = 0; k < DIMD; ++k) {
        float w = LD(W, offW + (long)k * DIMD + d, bf);
        a0 = fmaf(xr[0 * DIMD + k], w, a0);
        a1 = fmaf(xr[1 * DIMD + k], w, a1);
        a2 = fmaf(xr[2 * DIMD + k], w, a2);
        a3 = fmaf(xr[3 * DIMD + k], w, a3);
    }
    long ob = (row0 + rg * 4) * DIMD + d;
    out[ob + 0 * DIMD] = a0;
    out[ob + 1 * DIMD] = a1;
    out[ob + 2 * DIMD] = a2;
    out[ob + 3 * DIMD] = a3;
}

// Both transposes in one launch: z<BB -> (in0->out0, b=z), else (in1->out1).
__global__ void transpose_both(const float* __restrict__ in0, float* __restrict__ out0,
                               const float* __restrict__ in1, float* __restrict__ out1) {
    __shared__ float tile[32][33];
    int z = blockIdx.z;
    const float* in; float* outT; int b;
    if (z < BB) { in = in0; outT = out0; b = z; }
    else        { in = in1; outT = out1; b = z - BB; }
    int n0 = blockIdx.x * 32;
    int d0 = blockIdx.y * 32;
    int t = threadIdx.x;
    int tx = t & 31, ty = t >> 5;
    for (int r = ty; r < 32; r += 8)
        tile[r][tx] = in[((long)b * TT + n0 + r) * DIMD + d0 + tx];
    __syncthreads();
    for (int r = ty; r < 32; r += 8)
        outT[((long)b * DIMD + d0 + r) * TT + n0 + tx] = tile[tx][r];
}

// Pair energies. Block = (b, 2 ligand rows). Lane handles tt = 2t, 2t+1.
__global__ void pair_energy(const float* __restrict__ ligdc, const float* __restrict__ tgtdcT,
                            const float* __restrict__ ligA, const float* __restrict__ tgtAT,
                            const void* __restrict__ dcW2, const void* __restrict__ dcb2,
                            const void* __restrict__ AW2, const void* __restrict__ Ab2,
                            const void* __restrict__ lpos, const void* __restrict__ tpos,
                            const void* __restrict__ lrad, const void* __restrict__ trad,
                            const void* __restrict__ lval, const void* __restrict__ tval,
                            const void* __restrict__ ii, float* __restrict__ accum,
                            const int* __restrict__ flagp) {
    int bf = *flagp;
    int l0 = blockIdx.x * 2, b = blockIdx.y, t = threadIdx.x;
    __shared__ __align__(16) float sdc0[DIMD], sdc1[DIMD], sA0[DIMD], sA1[DIMD];
    __shared__ __align__(16) float w2dc[DIMD], w2A[DIMD];
    __shared__ float red[256];
    if (t < DIMD) {
        sdc0[t] = ligdc[((long)b * LL + l0) * DIMD + t];
        sA0[t]  = ligA [((long)b * LL + l0) * DIMD + t];
        w2dc[t] = LD(dcW2, t, bf);
        w2A[t]  = LD(AW2, t, bf);
    } else {
        int u = t - DIMD;
        sdc1[u] = ligdc[((long)b * LL + l0 + 1) * DIMD + u];
        sA1[u]  = ligA [((long)b * LL + l0 + 1) * DIMD + u];
    }
    __syncthreads();
    int tt0 = t * 2;
    const float* tdT = tgtdcT + (long)b * DIMD * TT;
    const float* taT = tgtAT  + (long)b * DIMD * TT;
    float adc00 = 0.0f, adc01 = 0.0f, adc10 = 0.0f, adc11 = 0.0f;
    float aA00 = 0.0f, aA01 = 0.0f, aA10 = 0.0f, aA11 = 0.0f;
    for (int i4 = 0; i4 < DIMD; i4 += 4) {
        float4 wd = *(const float4*)&w2dc[i4];
        float4 wa = *(const float4*)&w2A[i4];
        float4 v0d = *(const float4*)&sdc0[i4];
        float4 v1d = *(const float4*)&sdc1[i4];
        float4 v0a = *(const float4*)&sA0[i4];
        float4 v1a = *(const float4*)&sA1[i4];
        float wdv[4] = {wd.x, wd.y, wd.z, wd.w};
        float wav[4] = {wa.x, wa.y, wa.z, wa.w};
        float s0d[4] = {v0d.x, v0d.y, v0d.z, v0d.w};
        float s1d[4] = {v1d.x, v1d.y, v1d.z, v1d.w};
        float s0a[4] = {v0a.x, v0a.y, v0a.z, v0a.w};
        float s1a[4] = {v1a.x, v1a.y, v1a.z, v1a.w};
#pragma unroll
        for (int j = 0; j < 4; ++j) {
            float2 td = *(const float2*)&tdT[(long)(i4 + j) * TT + tt0];
            float2 ta = *(const float2*)&taT[(long)(i4 + j) * TT + tt0];
            adc00 = fmaf(fmaxf(td.x + s0d[j], 0.0f), wdv[j], adc00);
            adc01 = fmaf(fmaxf(td.y + s0d[j], 0.0f), wdv[j], adc01);
            adc10 = fmaf(fmaxf(td.x + s1d[j], 0.0f), wdv[j], adc10);
            adc11 = fmaf(fmaxf(td.y + s1d[j], 0.0f), wdv[j], adc11);
            aA00 = fmaf(fmaxf(ta.x + s0a[j], 0.0f), wav[j], aA00);
            aA01 = fmaf(fmaxf(ta.y + s0a[j], 0.0f), wav[j], aA01);
            aA10 = fmaf(fmaxf(ta.x + s1a[j], 0.0f), wav[j], aA10);
            aA11 = fmaf(fmaxf(ta.y + s1a[j], 0.0f), wav[j], aA11);
        }
    }
    float lx0 = LD(lpos, ((long)b * LL + l0) * 3 + 0, bf);
    float ly0 = LD(lpos, ((long)b * LL + l0) * 3 + 1, bf);
    float lz0 = LD(lpos, ((long)b * LL + l0) * 3 + 2, bf);
    float lx1 = LD(lpos, ((long)b * LL + l0 + 1) * 3 + 0, bf);
    float ly1 = LD(lpos, ((long)b * LL + l0 + 1) * 3 + 1, bf);
    float lz1 = LD(lpos, ((long)b * LL + l0 + 1) * 3 + 2, bf);
    float lr0 = LD(lrad, (long)b * LL + l0, bf);
    float lr1 = LD(lrad, (long)b * LL + l0 + 1, bf);
    float lv0 = LD(lval, (long)b * LL + l0, bf);
    float lv1 = LD(lval, (long)b * LL + l0 + 1, bf);
    float cdcb2 = LD(dcb2, 0, bf), cab2 = LD(Ab2, 0, bf);
    long iiA0 = ((long)(b * 3 + 0) * LL + l0) * TT;
    long iiB0 = ((long)(b * 3 + 1) * LL + l0) * TT;
    long iiC0 = ((long)(b * 3 + 2) * LL + l0) * TT;
    long iiA1 = iiA0 + TT, iiB1 = iiB0 + TT, iiC1 = iiC0 + TT;
    float p0 = 0.0f, p1 = 0.0f, p2 = 0.0f, p3 = 0.0f;
#pragma unroll
    for (int jj = 0; jj < 2; ++jj) {
        int tt = tt0 + jj;
        float tx = LD(tpos, ((long)b * TT + tt) * 3 + 0, bf);
        float ty = LD(tpos, ((long)b * TT + tt) * 3 + 1, bf);
        float tz = LD(tpos, ((long)b * TT + tt) * 3 + 2, bf);
        float tr = LD(trad, (long)b * TT + tt, bf);
        float tv = LD(tval, (long)b * TT + tt, bf);
#pragma unroll
        for (int li = 0; li < 2; ++li) {
            float dx = (li ? lx1 : lx0) - tx;
            float dy = (li ? ly1 : ly0) - ty;
            float dz = (li ? lz1 : lz0) - tz;
            float dm = sqrtf(dx * dx + dy * dy + dz * dz + 1e-10f);
            if (dm < 0.5f) dm = 1e10f;
            float adcv = jj ? (li ? adc11 : adc01) : (li ? adc10 : adc00);
            float aAv  = jj ? (li ? aA11  : aA01)  : (li ? aA10  : aA00);
            float dev = tanhf(adcv + cdcb2) * 0.2f;
            float vdws = (li ? lr1 : lr0) + tr + dev;
            float dm0 = (vdws < 1e-4f) ? 1.0f : vdws;
            float ratio = dm0 / dm;
            float r2 = ratio * ratio, r6 = r2 * r2 * r2, r12 = r6 * r6;
            float en = fminf(r12 - 2.0f * r6, 100.0f) * (li ? lv1 : lv0) * tv;
            float As = 1.0f / (1.0f + expf(-(aAv + cab2)));
            As = As * (0.0356f - 0.0178f) + 0.0178f;
            p0 = fmaf(As, en, p0);
            float dd = dm - vdws;
            float ramp = fminf(fmaxf(dd * (1.0f / -0.7f), 0.0f), 1.0f);
            p1 = fmaf(ramp, LD(ii, (li ? iiA1 : iiA0) + tt, bf), p1);
            p2 = fmaf(ramp, LD(ii, (li ? iiB1 : iiB0) + tt, bf), p2);
            float ramp2 = fminf(fmaxf(-dd + 1.5f, 0.0f), 1.0f);
            p3 = fmaf(ramp2, LD(ii, (li ? iiC1 : iiC0) + tt, bf), p3);
        }
    }
    for (int e = 0; e < 4; ++e) {
        float v = (e == 0) ? p0 : (e == 1) ? p1 : (e == 2) ? p2 : p3;
        red[t] = v; __syncthreads();
        for (int s = 128; s > 0; s >>= 1) { if (t < s) red[t] += red[t + s]; __syncthreads(); }
        if (t == 0) atomicAdd(&accum[b * 4 + e], red[0]);
        __syncthreads();
    }
}

__global__ void finalize(const float* __restrict__ accum, const void* __restrict__ hb,
                         const void* __restrict__ mc, const void* __restrict__ hyd,
                         const void* __restrict__ rc, const void* __restrict__ rotor,
                         void* __restrict__ out, const int* __restrict__ flagp) {
    int bf = *flagp;
    int t = threadIdx.x;  // 64 threads, use first 32
    if (t >= 32) return;
    int b = t >> 2, e = t & 3;
    float v = accum[t];
    if (e == 1) { float c = LD(hb, 0, bf);  v = -c * c * v; }
    else if (e == 2) { float c = LD(mc, 0, bf);  v = -c * c * v; }
    else if (e == 3) { float c = LD(hyd, 0, bf); v = -c * c * v; }
    float r = LD(rc, 0, bf);
    float den = 1.0f + r * r * LD(rotor, b, bf);
    float res = v / den;
    if (bf) ((bf16*)out)[t] = __float2bfloat16(res);
    else    ((float*)out)[t] = res;
}

extern "C" void kernel_launch(void* const* d_in, const int* in_sizes, int n_in,
                              void* d_out, int out_size, void* d_ws, size_t ws_size,
                              hipStream_t stream) {
    const void* ligand_h = d_in[0];
    const void* target_h = d_in[1];
    const void* ligand_adj = d_in[2];
    const void* target_adj = d_in[3];
    const void* interaction_indice = d_in[4];
    const void* ligand_pos = d_in[5];
    const void* target_pos = d_in[6];
    const void* rotor = d_in[7];
    const void* ligand_vdw = d_in[8];
    const void* target_vdw = d_in[9];
    const void* ligand_valid = d_in[10];
    const void* target_valid = d_in[11];
    const void* emb_W = d_in[12];
    const void* gat_W = d_in[13];
    const void* gat_Wb = d_in[14];
    const void* gat_A = d_in[15];
    const void* gat_gW = d_in[16];
    const void* gat_gb = d_in[17];
    const void* vdwA_W1 = d_in[18];
    const void* vdwA_b1 = d_in[19];
    const void* vdwA_W2 = d_in[20];
    const void* vdwA_b2 = d_in[21];
    const void* dc_W1 = d_in[22];
    const void* dc_b1 = d_in[23];
    const void* dc_W2 = d_in[24];
    const void* dc_b2 = d_in[25];
    const void* hbond_coeff = d_in[26];
    const void* metal_coeff = d_in[27];
    const void* hydrophobic_coeff = d_in[28];
    const void* rotor_coeff = d_in[29];

    float* ws = (float*)d_ws;
    size_t off = 0;
    float* lig_x = ws + off;  off += (size_t)BB * LL * DIMD;   // contiguous with tgt_x
    float* tgt_x = ws + off;  off += (size_t)BB * TT * DIMD;
    float* h_lig = ws + off;  off += (size_t)BB * LL * DIMD;   // contiguous with h_tgt
    float* h_tgt = ws + off;  off += (size_t)BB * TT * DIMD;
    float* hA_lig = ws + off; off += (size_t)BB * LL * DIMD;   // contiguous with hA_tgt
    float* hA_tgt = ws + off; off += (size_t)BB * TT * DIMD;
    float* accum = ws + off;  off += 32;
    int* flagp = (int*)(ws + off); off += 2;
    float* e_buf = ws + off;  off += (size_t)BB * TT * TT;     // 8MB target e; reused for transposes
    float* e_lig = ws + off;  off += (size_t)BB * LL * LL;     // 512KB ligand e
    float* part1 = ws + off;  off += (size_t)BB * (TT + LL) * DIMD; // split-K partials
    float* part1_t = part1;
    float* part1_l = part1 + (size_t)BB * TT * DIMD;
    // split-K partial 0 reuses hA buffers (dead after esym)
    float* part0_lig = hA_lig;
    float* part0_tgt = hA_tgt;
    // pair-MLP projections reuse h/hA buffers (dead after the GAT loop)
    float* ligdc = h_lig;    // merged out base (rows: lig then tgt)
    float* ligA = hA_lig;
    float* tgtdc = h_tgt;
    float* tgtA  = hA_tgt;
    // transposed target projections reuse e_buf (dead after the GAT loop)
    float* tgtdcT = e_buf;
    float* tgtAT  = e_buf + (size_t)BB * DIMD * TT;

    init_ws<<<1, 64, 0, stream>>>((const unsigned int*)emb_W, accum, flagp);

    // embeddings: x = h @ emb_W (both sides, one launch; out rows contiguous)
    embed_both<<<BB * (LL + TT), DIMD, 0, stream>>>(ligand_h, target_h, emb_W, lig_x, 54, flagp);

    const long ROWSPLIT = (long)BB * LL;   // multiple of 8
    for (int i = 0; i < 3; ++i) {
        long offW = (long)i * DIMD * DIMD;
        long offWb = (long)i * DIMD;
        long offgW = (long)i * 2 * DIMD;
        long offgb = i;
        // h = x@W + Wb ; hA = h@A  (both sides, one launch — shared weights)
        gemm_hha<<<BB * (LL + TT) / 8, 256, 0, stream>>>(
            lig_x, gat_W, gat_A, offW, gat_Wb, offWb, h_lig, hA_lig, flagp);
        // e (symmetric, upper tiles + mirror), both sides
        esym_both<<<dim3(TGT_TILES + LIG_TILES, BB), 256, 0, stream>>>(
            hA_tgt, h_tgt, e_buf, hA_lig, h_lig, e_lig);
        att_softmax_both<<<dim3(TT / 4 + LL / 4, BB), 256, 0, stream>>>(
            e_buf, e_lig, target_adj, ligand_adj, flagp);
        hp_gemm_both<<<dim3(20, 2, BB), 256, 0, stream>>>(
            e_buf, h_tgt, part0_tgt, part1_t, e_lig, h_lig, part0_lig, part1_l);
        gat_gate_both<<<dim3(TT / 4 + LL / 4, BB), 256, 0, stream>>>(
            tgt_x, lig_x, part0_tgt, part1_t, part0_lig, part1_l,
            gat_gW, offgW, gat_gb, offgb, flagp);
    }

    // pair-MLP projections, both weight sets in one launch
    proj_both<<<dim3(BB * (LL + TT) / 8, 2), 256, 0, stream>>>(
        lig_x, dc_W1, dc_b1, vdwA_W1, vdwA_b1, ROWSPLIT, ligdc, ligA, flagp);

    // transpose target projections for coalesced pair_energy reads (one launch)
    transpose_both<<<dim3(TT / 32, DIMD / 32, 2 * BB), 256, 0, stream>>>(
        tgtdc, tgtdcT, tgtA, tgtAT);

    pair_energy<<<dim3(LL / 2, BB), 256, 0, stream>>>(
        ligdc, tgtdcT, ligA, tgtAT, dc_W2, dc_b2, vdwA_W2, vdwA_b2,
        ligand_pos, target_pos, ligand_vdw, target_vdw,
        ligand_valid, target_valid, interaction_indice, accum, flagp);

    finalize<<<1, 64, 0, stream>>>(accum, hbond_coeff, metal_coeff,
                                   hydrophobic_coeff, rotor_coeff, rotor, d_out, flagp);
}

// Round 7
// 391.483 us; speedup vs baseline: 1.4134x; 1.1214x over previous
//
#include <hip/hip_runtime.h>
#include <hip/hip_bf16.h>
#include <math.h>

typedef __hip_bfloat16 bf16;

#define DIMD 128
#define BB 8
#define LL 128
#define TT 512

// esym tile params
#define BMT 64
#define BKT 32
#define TGT_TILES 36   // 8*9/2 upper-tri tiles (N=512 / 64)
#define LIG_TILES 3    // 2*3/2 upper-tri tiles (N=128 / 64)

// cvt'd weight region element offsets
#define CV_EMBW   0L
#define CV_GATW   (CV_EMBW + 54 * 128)
#define CV_GATA   (CV_GATW + 3 * 128 * 128)
#define CV_WB     (CV_GATA + 3 * 128 * 128)
#define CV_DCW1   (CV_WB + 3 * 128)
#define CV_VW1    (CV_DCW1 + 2 * 128 * 128)
#define CV_TOTAL  (CV_VW1 + 2 * 128 * 128)

// Runtime-dtype load of external inputs: bf==1 -> bf16, else f32.
__device__ __forceinline__ float LD(const void* p, long i, int bf) {
    if (bf) return __bfloat162float(((const bf16*)p)[i]);
    return ((const float*)p)[i];
}

// Detect external dtype from emb_W bit patterns + zero the accumulators.
__global__ void init_ws(const unsigned int* __restrict__ embw_raw,
                        float* __restrict__ accum, int* __restrict__ flagp) {
    int t = threadIdx.x;
    if (t < 32) accum[t] = 0.0f;
    if (t == 0) {
        int cnt = 0;
        for (int k = 0; k < 256; ++k) {
            unsigned int b = (embw_raw[k] >> 8) & 0xffu;
            unsigned int e = b & 0x7fu;
            if (e >= 0x38u && e <= 0x3fu) ++cnt;
        }
        *flagp = (cnt > 128) ? 1 : 0;
    }
}

// Convert the hot-loop weight matrices to f32 once (branch-free GEMMs after).
__global__ void cvt_weights(const void* __restrict__ embW, const void* __restrict__ gatW,
                            const void* __restrict__ gatA, const void* __restrict__ gatWb,
                            const void* __restrict__ dcW1, const void* __restrict__ vW1,
                            float* __restrict__ out, const int* __restrict__ flagp) {
    int bf = *flagp;
    long i = (long)blockIdx.x * 256 + threadIdx.x;
    if (i >= CV_TOTAL) return;
    float v;
    if (i < CV_GATW)      v = LD(embW, i - CV_EMBW, bf);
    else if (i < CV_GATA) v = LD(gatW, i - CV_GATW, bf);
    else if (i < CV_WB)   v = LD(gatA, i - CV_GATA, bf);
    else if (i < CV_DCW1) v = LD(gatWb, i - CV_WB, bf);
    else if (i < CV_VW1)  v = LD(dcW1, i - CV_DCW1, bf);
    else                  v = LD(vW1, i - CV_VW1, bf);
    out[i] = v;
}

// Both-sides embedding: rows [0, BB*LL) from Xl, rest from Xt. K=54. f32 W.
__global__ void embed_both(const void* __restrict__ Xl, const void* __restrict__ Xt,
                           const float* __restrict__ Wf, float* __restrict__ out,
                           int K, const int* __restrict__ flagp) {
    __shared__ float xrow[DIMD];
    int bf = *flagp;
    int row = blockIdx.x;
    int d = threadIdx.x;
    const void* X; long r;
    if (row < BB * LL) { X = Xl; r = row; }
    else               { X = Xt; r = row - BB * LL; }
    if (d < K) xrow[d] = LD(X, r * K + d, bf);
    __syncthreads();
    float acc = 0.0f;
    for (int k = 0; k < K; ++k)
        acc = fmaf(xrow[k], Wf[(long)k * DIMD + d], acc);
    out[(long)row * DIMD + d] = acc;
}

// Fused h = x@W + Wb ; hA = h@A. 4 rows/block (1280 blocks -> 20 waves/CU),
// 256 threads = 2 row-groups x 128 cols, 2 acc chains per phase. f32 weights.
__global__ void gemm_hha4(const float* __restrict__ X, const float* __restrict__ Wf,
                          const float* __restrict__ Af, const float* __restrict__ Wbf,
                          int layer, float* __restrict__ hout, float* __restrict__ hAout) {
    __shared__ float xs[4][DIMD];
    __shared__ float hs[4][DIMD];
    long row0 = (long)blockIdx.x * 4;
    int d = threadIdx.x & 127, rg = threadIdx.x >> 7;
    xs[rg * 2 + 0][d] = X[(row0 + rg * 2 + 0) * DIMD + d];
    xs[rg * 2 + 1][d] = X[(row0 + rg * 2 + 1) * DIMD + d];
    __syncthreads();
    const float* W = Wf + (long)layer * DIMD * DIMD;
    const float* A = Af + (long)layer * DIMD * DIMD;
    float b = Wbf[layer * DIMD + d];
    float h0 = b, h1 = b;
    const float* x0 = xs[rg * 2];
    const float* x1 = xs[rg * 2 + 1];
#pragma unroll 8
    for (int k = 0; k < DIMD; ++k) {
        float w = W[(long)k * DIMD + d];
        h0 = fmaf(x0[k], w, h0);
        h1 = fmaf(x1[k], w, h1);
    }
    long ob = (row0 + rg * 2) * DIMD + d;
    hout[ob] = h0; hout[ob + DIMD] = h1;
    hs[rg * 2][d] = h0; hs[rg * 2 + 1][d] = h1;
    __syncthreads();
    float a0 = 0.0f, a1 = 0.0f;
    const float* g0 = hs[rg * 2];
    const float* g1 = hs[rg * 2 + 1];
#pragma unroll 8
    for (int k = 0; k < DIMD; ++k) {
        float w = A[(long)k * DIMD + d];
        a0 = fmaf(g0[k], w, a0);
        a1 = fmaf(g1[k], w, a1);
    }
    hAout[ob] = a0;
    hAout[ob + DIMD] = a1;
}

// e[b,j,k] = hA_j . h_k + h_j . hA_k  (symmetric!). Batched GEMM, K=256.
// Upper-triangle tiles only; mirror-write the transpose into the lower tile.
__global__ void esym_both(const float* __restrict__ hA_t, const float* __restrict__ h_t,
                          float* __restrict__ e_t,
                          const float* __restrict__ hA_l, const float* __restrict__ h_l,
                          float* __restrict__ e_l) {
    __shared__ float At[BKT][BMT + 4];
    __shared__ float Bt[BKT][BMT + 4];
    int idx = blockIdx.x, b = blockIdx.y, t = threadIdx.x;
    const float *hA, *h; float* e; int N;
    if (idx < TGT_TILES) { hA = hA_t; h = h_t; e = e_t; N = TT; }
    else { idx -= TGT_TILES; hA = hA_l; h = h_l; e = e_l; N = LL; }
    int jt = (int)((sqrtf(8.0f * idx + 1.0f) - 1.0f) * 0.5f);
    while ((jt + 1) * (jt + 2) / 2 <= idx) ++jt;
    while (jt * (jt + 1) / 2 > idx) --jt;
    int kt = idx - jt * (jt + 1) / 2;   // kt <= jt
    const float* hAb = hA + (long)b * N * DIMD;
    const float* hb  = h  + (long)b * N * DIMD;
    int tm = t & 15, tn = t >> 4;
    int k4 = (t & 7) * 4;
    int row0 = t >> 3;
    float acc[4][4];
#pragma unroll
    for (int i = 0; i < 4; ++i)
#pragma unroll
        for (int jj = 0; jj < 4; ++jj) acc[i][jj] = 0.0f;

#pragma unroll
    for (int c = 0; c < 8; ++c) {
        const float* Ap = (c < 4) ? hAb : hb;
        const float* Bp = (c < 4) ? hb : hAb;
        int ko = (c & 3) * BKT;
        __syncthreads();
#pragma unroll
        for (int rr = 0; rr < 2; ++rr) {
            int row = row0 + rr * 32;
            float4 av = *(const float4*)&Ap[(long)(jt * BMT + row) * DIMD + ko + k4];
            float4 bv = *(const float4*)&Bp[(long)(kt * BMT + row) * DIMD + ko + k4];
            At[k4 + 0][row] = av.x; At[k4 + 1][row] = av.y;
            At[k4 + 2][row] = av.z; At[k4 + 3][row] = av.w;
            Bt[k4 + 0][row] = bv.x; Bt[k4 + 1][row] = bv.y;
            Bt[k4 + 2][row] = bv.z; Bt[k4 + 3][row] = bv.w;
        }
        __syncthreads();
#pragma unroll
        for (int k = 0; k < BKT; ++k) {
            float4 a4 = *(const float4*)&At[k][tm * 4];
            float4 b4 = *(const float4*)&Bt[k][tn * 4];
            float A[4] = {a4.x, a4.y, a4.z, a4.w};
            float Bv[4] = {b4.x, b4.y, b4.z, b4.w};
#pragma unroll
            for (int i = 0; i < 4; ++i)
#pragma unroll
                for (int jj = 0; jj < 4; ++jj)
                    acc[i][jj] = fmaf(A[i], Bv[jj], acc[i][jj]);
        }
    }
    long ebN = (long)b * N;
    long ebase = (ebN + jt * BMT + tm * 4) * N + kt * BMT + tn * 4;
#pragma unroll
    for (int i = 0; i < 4; ++i) {
        float4 v;
        v.x = acc[i][0]; v.y = acc[i][1]; v.z = acc[i][2]; v.w = acc[i][3];
        *(float4*)&e[ebase + (long)i * N] = v;
    }
    if (jt != kt) {   // mirror tile (transpose), also float4-coalesced
        long mbase = (ebN + kt * BMT + tn * 4) * N + jt * BMT + tm * 4;
#pragma unroll
        for (int jj = 0; jj < 4; ++jj) {
            float4 v;
            v.x = acc[0][jj]; v.y = acc[1][jj]; v.z = acc[2][jj]; v.w = acc[3][jj];
            *(float4*)&e[mbase + (long)jj * N] = v;
        }
    }
}

// att row softmax, one WAVE per row (no barriers). In-place on e.
template<int CNT>
__device__ __forceinline__ void softmax_row(float* __restrict__ erow,
                                            const void* __restrict__ adj,
                                            long adjbase, int bf) {
    int lane = threadIdx.x & 63;
    float vals[CNT], av[CNT];
    float m = -3.4e38f;
#pragma unroll
    for (int i = 0; i < CNT; ++i) {
        int k = lane + i * 64;
        float a = LD(adj, adjbase + k, bf);
        float v = (a > 0.0f) ? erow[k] : -9e15f;
        av[i] = a; vals[i] = v;
        m = fmaxf(m, v);
    }
#pragma unroll
    for (int s = 32; s > 0; s >>= 1) m = fmaxf(m, __shfl_xor(m, s));
    float sum = 0.0f;
#pragma unroll
    for (int i = 0; i < CNT; ++i) { vals[i] = expf(vals[i] - m); sum += vals[i]; }
#pragma unroll
    for (int s = 32; s > 0; s >>= 1) sum += __shfl_xor(sum, s);
    float inv = 1.0f / sum;
#pragma unroll
    for (int i = 0; i < CNT; ++i)
        erow[lane + i * 64] = vals[i] * av[i] * inv;
}

// x < TT/4: target rows; else ligand rows. 4 waves = 4 rows per block.
__global__ void att_softmax_both(float* __restrict__ e_t, float* __restrict__ e_l,
                                 const void* __restrict__ adj_t, const void* __restrict__ adj_l,
                                 const int* __restrict__ flagp) {
    int bf = *flagp;
    int b = blockIdx.y, x = blockIdx.x;
    int jr = threadIdx.x >> 6;
    if (x < TT / 4) {
        int j = x * 4 + jr;
        long base = ((long)b * TT + j) * TT;
        softmax_row<8>(e_t + base, adj_t, base, bf);
    } else {
        int j = (x - TT / 4) * 4 + jr;
        long base = ((long)b * LL + j) * LL;
        softmax_row<2>(e_l + base, adj_l, base, bf);
    }
}

// Partial hp GEMM: part[b][j][d] = sum over k-chunk of att[b][j][k]*h[b][k][d]
// BM=32, BN=128, BK=32, 256 threads, 4x4 acc, split-K=2 via blockIdx.y.
// Grid x: [0,16) target row-tiles, [16,20) ligand row-tiles.
__global__ void hp_gemm_both(const float* __restrict__ att_t, const float* __restrict__ h_t,
                             float* __restrict__ p0_t, float* __restrict__ p1_t,
                             const float* __restrict__ att_l, const float* __restrict__ h_l,
                             float* __restrict__ p0_l, float* __restrict__ p1_l) {
    __shared__ float At[32][36];
    __shared__ float Ht[32][DIMD];
    int jt = blockIdx.x, kc = blockIdx.y, b = blockIdx.z;
    int t = threadIdx.x;
    const float *att, *h; float *part0, *part1; int N;
    if (jt < 16) { att = att_t; h = h_t; part0 = p0_t; part1 = p1_t; N = TT; }
    else { jt -= 16; att = att_l; h = h_l; part0 = p0_l; part1 = p1_l; N = LL; }
    const float* attb = att + (long)b * N * N;
    const float* hb = h + (long)b * N * DIMD;
    int tm = t & 7, tn = t >> 3;
    float acc[4][4] = {};
    int kchunk = N / 2;
    int kbeg = kc * kchunk;
    int ar = t >> 3;
    int ac4 = (t & 7) * 4;
    int hk = t >> 5;
    int hc4 = (t & 31) * 4;
    for (int k0 = kbeg; k0 < kbeg + kchunk; k0 += 32) {
        __syncthreads();
        float4 av = *(const float4*)&attb[(long)(jt * 32 + ar) * N + k0 + ac4];
        At[ac4 + 0][ar] = av.x; At[ac4 + 1][ar] = av.y;
        At[ac4 + 2][ar] = av.z; At[ac4 + 3][ar] = av.w;
#pragma unroll
        for (int p = 0; p < 4; ++p)
            *(float4*)&Ht[hk + p * 8][hc4] = *(const float4*)&hb[(long)(k0 + hk + p * 8) * DIMD + hc4];
        __syncthreads();
#pragma unroll
        for (int k = 0; k < 32; ++k) {
            float4 a4 = *(const float4*)&At[k][tm * 4];
            float4 h4 = *(const float4*)&Ht[k][tn * 4];
            float A[4] = {a4.x, a4.y, a4.z, a4.w};
            float H[4] = {h4.x, h4.y, h4.z, h4.w};
#pragma unroll
            for (int i = 0; i < 4; ++i)
#pragma unroll
                for (int jj = 0; jj < 4; ++jj)
                    acc[i][jj] = fmaf(A[i], H[jj], acc[i][jj]);
        }
    }
    float* outp = (kc == 0) ? part0 : part1;
    long obase = ((long)b * N + jt * 32 + tm * 4) * DIMD + tn * 4;
#pragma unroll
    for (int i = 0; i < 4; ++i) {
        float4 v; v.x = acc[i][0]; v.y = acc[i][1]; v.z = acc[i][2]; v.w = acc[i][3];
        *(float4*)&outp[obase + (long)i * DIMD] = v;
    }
}

// Gate: hp = relu(part0+part1); coeff = sigmoid(concat(x,hp)@gW+gb); x updated.
// One WAVE per row; x < TT/4 -> target rows, else ligand.
__global__ void gat_gate_both(float* __restrict__ x_t, float* __restrict__ x_l,
                              const float* __restrict__ p0_t, const float* __restrict__ p1_t,
                              const float* __restrict__ p0_l, const float* __restrict__ p1_l,
                              const void* __restrict__ gW, long offgW,
                              const void* __restrict__ gb, long offgb,
                              const int* __restrict__ flagp) {
    int bf = *flagp;
    int b = blockIdx.y, x = blockIdx.x;
    int jr = threadIdx.x >> 6, lane = threadIdx.x & 63;
    float* xb; const float *part0, *part1; long rbase;
    if (x < TT / 4) {
        int j = x * 4 + jr;
        rbase = ((long)b * TT + j) * DIMD;
        xb = x_t; part0 = p0_t; part1 = p1_t;
    } else {
        int j = (x - TT / 4) * 4 + jr;
        rbase = ((long)b * LL + j) * DIMD;
        xb = x_l; part0 = p0_l; part1 = p1_l;
    }
    float* xrow = xb + rbase;
    float hp0 = fmaxf(part0[rbase + lane] + part1[rbase + lane], 0.0f);
    float hp1 = fmaxf(part0[rbase + lane + 64] + part1[rbase + lane + 64], 0.0f);
    float x0 = xrow[lane], x1 = xrow[lane + 64];
    float g = x0 * LD(gW, offgW + lane, bf) + x1 * LD(gW, offgW + lane + 64, bf)
            + hp0 * LD(gW, offgW + DIMD + lane, bf) + hp1 * LD(gW, offgW + DIMD + lane + 64, bf);
#pragma unroll
    for (int s = 32; s > 0; s >>= 1) g += __shfl_xor(g, s);
    g += LD(gb, offgb, bf);
    float coeff = 1.0f / (1.0f + expf(-g));
    xrow[lane] = coeff * x0 + (1.0f - coeff) * hp0;
    xrow[lane + 64] = coeff * x1 + (1.0f - coeff) * hp1;
}

// Both pair-MLP projections, 4 rows/block, f32 weights.
// blockIdx.y: 0=dc set, 1=vdwA set. Rows < rowsplit use W1[:D] + b1; rest W1[D:].
__global__ void proj_both4(const float* __restrict__ X,
                           const float* __restrict__ Wdcf, const void* __restrict__ bdc,
                           const float* __restrict__ WAf, const void* __restrict__ bA,
                           long rowsplit, float* __restrict__ outdc, float* __restrict__ outA,
                           const int* __restrict__ flagp) {
    __shared__ float xs[4][DIMD];
    int bf = *flagp;
    const float* Wf; const void* bias; float* out;
    if (blockIdx.y == 0) { Wf = Wdcf; bias = bdc; out = outdc; }
    else                 { Wf = WAf;  bias = bA;  out = outA; }
    long row0 = (long)blockIdx.x * 4;
    int d = threadIdx.x & 127, rg = threadIdx.x >> 7;
    int sideb = row0 >= rowsplit;
    const float* W = Wf + (sideb ? (long)DIMD * DIMD : 0);
    xs[rg * 2 + 0][d] = X[(row0 + rg * 2 + 0) * DIMD + d];
    xs[rg * 2 + 1][d] = X[(row0 + rg * 2 + 1) * DIMD + d];
    __syncthreads();
    float b0 = sideb ? 0.0f : LD(bias, d, bf);
    float a0 = b0, a1 = b0;
    const float* x0 = xs[rg * 2];
    const float* x1 = xs[rg * 2 + 1];
#pragma unroll 8
    for (int k = 0; k < DIMD; ++k) {
        float w = W[(long)k * DIMD + d];
        a0 = fmaf(x0[k], w, a0);
        a1 = fmaf(x1[k], w, a1);
    }
    long ob = (row0 + rg * 2) * DIMD + d;
    out[ob] = a0;
    out[ob + DIMD] = a1;
}

// Both transposes in one launch: z<BB -> (in0->out0, b=z), else (in1->out1).
__global__ void transpose_both(const float* __restrict__ in0, float* __restrict__ out0,
                               const float* __restrict__ in1, float* __restrict__ out1) {
    __shared__ float tile[32][33];
    int z = blockIdx.z;
    const float* in; float* outT; int b;
    if (z < BB) { in = in0; outT = out0; b = z; }
    else        { in = in1; outT = out1; b = z - BB; }
    int n0 = blockIdx.x * 32;
    int d0 = blockIdx.y * 32;
    int t = threadIdx.x;
    int tx = t & 31, ty = t >> 5;
    for (int r = ty; r < 32; r += 8)
        tile[r][tx] = in[((long)b * TT + n0 + r) * DIMD + d0 + tx];
    __syncthreads();
    for (int r = ty; r < 32; r += 8)
        outT[((long)b * DIMD + d0 + r) * TT + n0 + tx] = tile[tx][r];
}

// Pair energies. Block = (b, 2 ligand rows). Lane handles tt = 2t, 2t+1.
__global__ void pair_energy(const float* __restrict__ ligdc, const float* __restrict__ tgtdcT,
                            const float* __restrict__ ligA, const float* __restrict__ tgtAT,
                            const void* __restrict__ dcW2, const void* __restrict__ dcb2,
                            const void* __restrict__ AW2, const void* __restrict__ Ab2,
                            const void* __restrict__ lpos, const void* __restrict__ tpos,
                            const void* __restrict__ lrad, const void* __restrict__ trad,
                            const void* __restrict__ lval, const void* __restrict__ tval,
                            const void* __restrict__ ii, float* __restrict__ accum,
                            const int* __restrict__ flagp) {
    int bf = *flagp;
    int l0 = blockIdx.x * 2, b = blockIdx.y, t = threadIdx.x;
    __shared__ __align__(16) float sdc0[DIMD], sdc1[DIMD], sA0[DIMD], sA1[DIMD];
    __shared__ __align__(16) float w2dc[DIMD], w2A[DIMD];
    __shared__ float red[256];
    if (t < DIMD) {
        sdc0[t] = ligdc[((long)b * LL + l0) * DIMD + t];
        sA0[t]  = ligA [((long)b * LL + l0) * DIMD + t];
        w2dc[t] = LD(dcW2, t, bf);
        w2A[t]  = LD(AW2, t, bf);
    } else {
        int u = t - DIMD;
        sdc1[u] = ligdc[((long)b * LL + l0 + 1) * DIMD + u];
        sA1[u]  = ligA [((long)b * LL + l0 + 1) * DIMD + u];
    }
    __syncthreads();
    int tt0 = t * 2;
    const float* tdT = tgtdcT + (long)b * DIMD * TT;
    const float* taT = tgtAT  + (long)b * DIMD * TT;
    float adc00 = 0.0f, adc01 = 0.0f, adc10 = 0.0f, adc11 = 0.0f;
    float aA00 = 0.0f, aA01 = 0.0f, aA10 = 0.0f, aA11 = 0.0f;
    for (int i4 = 0; i4 < DIMD; i4 += 4) {
        float4 wd = *(const float4*)&w2dc[i4];
        float4 wa = *(const float4*)&w2A[i4];
        float4 v0d = *(const float4*)&sdc0[i4];
        float4 v1d = *(const float4*)&sdc1[i4];
        float4 v0a = *(const float4*)&sA0[i4];
        float4 v1a = *(const float4*)&sA1[i4];
        float wdv[4] = {wd.x, wd.y, wd.z, wd.w};
        float wav[4] = {wa.x, wa.y, wa.z, wa.w};
        float s0d[4] = {v0d.x, v0d.y, v0d.z, v0d.w};
        float s1d[4] = {v1d.x, v1d.y, v1d.z, v1d.w};
        float s0a[4] = {v0a.x, v0a.y, v0a.z, v0a.w};
        float s1a[4] = {v1a.x, v1a.y, v1a.z, v1a.w};
#pragma unroll
        for (int j = 0; j < 4; ++j) {
            float2 td = *(const float2*)&tdT[(long)(i4 + j) * TT + tt0];
            float2 ta = *(const float2*)&taT[(long)(i4 + j) * TT + tt0];
            adc00 = fmaf(fmaxf(td.x + s0d[j], 0.0f), wdv[j], adc00);
            adc01 = fmaf(fmaxf(td.y + s0d[j], 0.0f), wdv[j], adc01);
            adc10 = fmaf(fmaxf(td.x + s1d[j], 0.0f), wdv[j], adc10);
            adc11 = fmaf(fmaxf(td.y + s1d[j], 0.0f), wdv[j], adc11);
            aA00 = fmaf(fmaxf(ta.x + s0a[j], 0.0f), wav[j], aA00);
            aA01 = fmaf(fmaxf(ta.y + s0a[j], 0.0f), wav[j], aA01);
            aA10 = fmaf(fmaxf(ta.x + s1a[j], 0.0f), wav[j], aA10);
            aA11 = fmaf(fmaxf(ta.y + s1a[j], 0.0f), wav[j], aA11);
        }
    }
    float lx0 = LD(lpos, ((long)b * LL + l0) * 3 + 0, bf);
    float ly0 = LD(lpos, ((long)b * LL + l0) * 3 + 1, bf);
    float lz0 = LD(lpos, ((long)b * LL + l0) * 3 + 2, bf);
    float lx1 = LD(lpos, ((long)b * LL + l0 + 1) * 3 + 0, bf);
    float ly1 = LD(lpos, ((long)b * LL + l0 + 1) * 3 + 1, bf);
    float lz1 = LD(lpos, ((long)b * LL + l0 + 1) * 3 + 2, bf);
    float lr0 = LD(lrad, (long)b * LL + l0, bf);
    float lr1 = LD(lrad, (long)b * LL + l0 + 1, bf);
    float lv0 = LD(lval, (long)b * LL + l0, bf);
    float lv1 = LD(lval, (long)b * LL + l0 + 1, bf);
    float cdcb2 = LD(dcb2, 0, bf), cab2 = LD(Ab2, 0, bf);
    long iiA0 = ((long)(b * 3 + 0) * LL + l0) * TT;
    long iiB0 = ((long)(b * 3 + 1) * LL + l0) * TT;
    long iiC0 = ((long)(b * 3 + 2) * LL + l0) * TT;
    long iiA1 = iiA0 + TT, iiB1 = iiB0 + TT, iiC1 = iiC0 + TT;
    float p0 = 0.0f, p1 = 0.0f, p2 = 0.0f, p3 = 0.0f;
#pragma unroll
    for (int jj = 0; jj < 2; ++jj) {
        int tt = tt0 + jj;
        float tx = LD(tpos, ((long)b * TT + tt) * 3 + 0, bf);
        float ty = LD(tpos, ((long)b * TT + tt) * 3 + 1, bf);
        float tz = LD(tpos, ((long)b * TT + tt) * 3 + 2, bf);
        float tr = LD(trad, (long)b * TT + tt, bf);
        float tv = LD(tval, (long)b * TT + tt, bf);
#pragma unroll
        for (int li = 0; li < 2; ++li) {
            float dx = (li ? lx1 : lx0) - tx;
            float dy = (li ? ly1 : ly0) - ty;
            float dz = (li ? lz1 : lz0) - tz;
            float dm = sqrtf(dx * dx + dy * dy + dz * dz + 1e-10f);
            if (dm < 0.5f) dm = 1e10f;
            float adcv = jj ? (li ? adc11 : adc01) : (li ? adc10 : adc00);
            float aAv  = jj ? (li ? aA11  : aA01)  : (li ? aA10  : aA00);
            float dev = tanhf(adcv + cdcb2) * 0.2f;
            float vdws = (li ? lr1 : lr0) + tr + dev;
            float dm0 = (vdws < 1e-4f) ? 1.0f : vdws;
            float ratio = dm0 / dm;
            float r2 = ratio * ratio, r6 = r2 * r2 * r2, r12 = r6 * r6;
            float en = fminf(r12 - 2.0f * r6, 100.0f) * (li ? lv1 : lv0) * tv;
            float As = 1.0f / (1.0f + expf(-(aAv + cab2)));
            As = As * (0.0356f - 0.0178f) + 0.0178f;
            p0 = fmaf(As, en, p0);
            float dd = dm - vdws;
            float ramp = fminf(fmaxf(dd * (1.0f / -0.7f), 0.0f), 1.0f);
            p1 = fmaf(ramp, LD(ii, (li ? iiA1 : iiA0) + tt, bf), p1);
            p2 = fmaf(ramp, LD(ii, (li ? iiB1 : iiB0) + tt, bf), p2);
            float ramp2 = fminf(fmaxf(-dd + 1.5f, 0.0f), 1.0f);
            p3 = fmaf(ramp2, LD(ii, (li ? iiC1 : iiC0) + tt, bf), p3);
        }
    }
    for (int e = 0; e < 4; ++e) {
        float v = (e == 0) ? p0 : (e == 1) ? p1 : (e == 2) ? p2 : p3;
        red[t] = v; __syncthreads();
        for (int s = 128; s > 0; s >>= 1) { if (t < s) red[t] += red[t + s]; __syncthreads(); }
        if (t == 0) atomicAdd(&accum[b * 4 + e], red[0]);
        __syncthreads();
    }
}

__global__ void finalize(const float* __restrict__ accum, const void* __restrict__ hb,
                         const void* __restrict__ mc, const void* __restrict__ hyd,
                         const void* __restrict__ rc, const void* __restrict__ rotor,
                         void* __restrict__ out, const int* __restrict__ flagp) {
    int bf = *flagp;
    int t = threadIdx.x;  // 64 threads, use first 32
    if (t >= 32) return;
    int b = t >> 2, e = t & 3;
    float v = accum[t];
    if (e == 1) { float c = LD(hb, 0, bf);  v = -c * c * v; }
    else if (e == 2) { float c = LD(mc, 0, bf);  v = -c * c * v; }
    else if (e == 3) { float c = LD(hyd, 0, bf); v = -c * c * v; }
    float r = LD(rc, 0, bf);
    float den = 1.0f + r * r * LD(rotor, b, bf);
    float res = v / den;
    if (bf) ((bf16*)out)[t] = __float2bfloat16(res);
    else    ((float*)out)[t] = res;
}

extern "C" void kernel_launch(void* const* d_in, const int* in_sizes, int n_in,
                              void* d_out, int out_size, void* d_ws, size_t ws_size,
                              hipStream_t stream) {
    const void* ligand_h = d_in[0];
    const void* target_h = d_in[1];
    const void* ligand_adj = d_in[2];
    const void* target_adj = d_in[3];
    const void* interaction_indice = d_in[4];
    const void* ligand_pos = d_in[5];
    const void* target_pos = d_in[6];
    const void* rotor = d_in[7];
    const void* ligand_vdw = d_in[8];
    const void* target_vdw = d_in[9];
    const void* ligand_valid = d_in[10];
    const void* target_valid = d_in[11];
    const void* emb_W = d_in[12];
    const void* gat_W = d_in[13];
    const void* gat_Wb = d_in[14];
    const void* gat_A = d_in[15];
    const void* gat_gW = d_in[16];
    const void* gat_gb = d_in[17];
    const void* vdwA_W1 = d_in[18];
    const void* vdwA_b1 = d_in[19];
    const void* vdwA_W2 = d_in[20];
    const void* vdwA_b2 = d_in[21];
    const void* dc_W1 = d_in[22];
    const void* dc_b1 = d_in[23];
    const void* dc_W2 = d_in[24];
    const void* dc_b2 = d_in[25];
    const void* hbond_coeff = d_in[26];
    const void* metal_coeff = d_in[27];
    const void* hydrophobic_coeff = d_in[28];
    const void* rotor_coeff = d_in[29];

    float* ws = (float*)d_ws;
    size_t off = 0;
    float* lig_x = ws + off;  off += (size_t)BB * LL * DIMD;   // contiguous with tgt_x
    float* tgt_x = ws + off;  off += (size_t)BB * TT * DIMD;
    float* h_lig = ws + off;  off += (size_t)BB * LL * DIMD;   // contiguous with h_tgt
    float* h_tgt = ws + off;  off += (size_t)BB * TT * DIMD;
    float* hA_lig = ws + off; off += (size_t)BB * LL * DIMD;   // contiguous with hA_tgt
    float* hA_tgt = ws + off; off += (size_t)BB * TT * DIMD;
    float* accum = ws + off;  off += 32;
    int* flagp = (int*)(ws + off); off += 2;
    float* e_buf = ws + off;  off += (size_t)BB * TT * TT;     // 8MB target e; reused for transposes
    float* e_lig = ws + off;  off += (size_t)BB * LL * LL;     // 512KB ligand e
    float* part1 = ws + off;  off += (size_t)BB * (TT + LL) * DIMD; // split-K partials
    float* cvw   = ws + off;  off += (size_t)CV_TOTAL;         // f32 weight copies
    float* part1_t = part1;
    float* part1_l = part1 + (size_t)BB * TT * DIMD;
    // split-K partial 0 reuses hA buffers (dead after esym)
    float* part0_lig = hA_lig;
    float* part0_tgt = hA_tgt;
    // pair-MLP projections reuse h/hA buffers (dead after the GAT loop)
    float* ligdc = h_lig;    // merged out base (rows: lig then tgt)
    float* ligA = hA_lig;
    float* tgtdc = h_tgt;
    float* tgtA  = hA_tgt;
    // transposed target projections reuse e_buf (dead after the GAT loop)
    float* tgtdcT = e_buf;
    float* tgtAT  = e_buf + (size_t)BB * DIMD * TT;
    // cvt'd weight pointers
    float* wEmb = cvw + CV_EMBW;
    float* wGat = cvw + CV_GATW;
    float* wGatA = cvw + CV_GATA;
    float* wWb  = cvw + CV_WB;
    float* wDc1 = cvw + CV_DCW1;
    float* wV1  = cvw + CV_VW1;

    init_ws<<<1, 64, 0, stream>>>((const unsigned int*)emb_W, accum, flagp);
    cvt_weights<<<(CV_TOTAL + 255) / 256, 256, 0, stream>>>(
        emb_W, gat_W, gat_A, gat_Wb, dc_W1, vdwA_W1, cvw, flagp);

    // embeddings: x = h @ emb_W (both sides, one launch; out rows contiguous)
    embed_both<<<BB * (LL + TT), DIMD, 0, stream>>>(ligand_h, target_h, wEmb, lig_x, 54, flagp);

    const long ROWSPLIT = (long)BB * LL;   // multiple of 4
    for (int i = 0; i < 3; ++i) {
        long offgW = (long)i * 2 * DIMD;
        long offgb = i;
        // h = x@W + Wb ; hA = h@A  (both sides, one launch — f32 weights)
        gemm_hha4<<<BB * (LL + TT) / 4, 256, 0, stream>>>(
            lig_x, wGat, wGatA, wWb, i, h_lig, hA_lig);
        // e (symmetric, upper tiles + mirror), both sides
        esym_both<<<dim3(TGT_TILES + LIG_TILES, BB), 256, 0, stream>>>(
            hA_tgt, h_tgt, e_buf, hA_lig, h_lig, e_lig);
        att_softmax_both<<<dim3(TT / 4 + LL / 4, BB), 256, 0, stream>>>(
            e_buf, e_lig, target_adj, ligand_adj, flagp);
        hp_gemm_both<<<dim3(20, 2, BB), 256, 0, stream>>>(
            e_buf, h_tgt, part0_tgt, part1_t, e_lig, h_lig, part0_lig, part1_l);
        gat_gate_both<<<dim3(TT / 4 + LL / 4, BB), 256, 0, stream>>>(
            tgt_x, lig_x, part0_tgt, part1_t, part0_lig, part1_l,
            gat_gW, offgW, gat_gb, offgb, flagp);
    }

    // pair-MLP projections, both weight sets in one launch, 4 rows/block
    proj_both4<<<dim3(BB * (LL + TT) / 4, 2), 256, 0, stream>>>(
        lig_x, wDc1, dc_b1, wV1, vdwA_b1, ROWSPLIT, ligdc, ligA, flagp);

    // transpose target projections for coalesced pair_energy reads (one launch)
    transpose_both<<<dim3(TT / 32, DIMD / 32, 2 * BB), 256, 0, stream>>>(
        tgtdc, tgtdcT, tgtA, tgtAT);

    pair_energy<<<dim3(LL / 2, BB), 256, 0, stream>>>(
        ligdc, tgtdcT, ligA, tgtAT, dc_W2, dc_b2, vdwA_W2, vdwA_b2,
        ligand_pos, target_pos, ligand_vdw, target_vdw,
        ligand_valid, target_valid, interaction_indice, accum, flagp);

    finalize<<<1, 64, 0, stream>>>(accum, hbond_coeff, metal_coeff,
                                   hydrophobic_coeff, rotor_coeff, rotor, d_out, flagp);
}

// Round 8
// 384.417 us; speedup vs baseline: 1.4394x; 1.0184x over previous
//
#include <hip/hip_runtime.h>
#include <hip/hip_bf16.h>
#include <math.h>

typedef __hip_bfloat16 bf16;

#define DIMD 128
#define BB 8
#define LL 128
#define TT 512

// esym tile params
#define BMT 64
#define BKT 32
#define TGT_TILES 36   // 8*9/2 upper-tri tiles (N=512 / 64)
#define LIG_TILES 3    // 2*3/2 upper-tri tiles (N=128 / 64)

// cvt'd f32 weight region element offsets
#define CV_EMBW   0L
#define CV_GATW   (CV_EMBW + 54 * 128)
#define CV_GATA   (CV_GATW + 3 * 128 * 128)
#define CV_WB     (CV_GATA + 3 * 128 * 128)
#define CV_GGW    (CV_WB + 3 * 128)
#define CV_GGB    (CV_GGW + 3 * 2 * 128)
#define CV_DCW1   (CV_GGB + 4)
#define CV_VW1    (CV_DCW1 + 2 * 128 * 128)
#define CV_TOTAL  (CV_VW1 + 2 * 128 * 128)

// Runtime-dtype load of external inputs: bf==1 -> bf16, else f32.
__device__ __forceinline__ float LD(const void* p, long i, int bf) {
    if (bf) return __bfloat162float(((const bf16*)p)[i]);
    return ((const float*)p)[i];
}

// One-time: detect dtype (self-detect per block, no dependency), zero accum,
// publish flagp, convert hot weights to f32 (branch-free GEMMs afterwards).
__global__ void init_cvt(const unsigned int* __restrict__ embw_raw,
                         const void* __restrict__ embW, const void* __restrict__ gatW,
                         const void* __restrict__ gatA, const void* __restrict__ gatWb,
                         const void* __restrict__ ggW, const void* __restrict__ ggb,
                         const void* __restrict__ dcW1, const void* __restrict__ vW1,
                         float* __restrict__ out, float* __restrict__ accum,
                         int* __restrict__ flagp) {
    __shared__ int cnts;
    int t = threadIdx.x;
    if (t == 0) cnts = 0;
    __syncthreads();
    unsigned int bword = (embw_raw[t] >> 8) & 0xffu;
    unsigned int e = bword & 0x7fu;
    if (e >= 0x38u && e <= 0x3fu) atomicAdd(&cnts, 1);
    __syncthreads();
    int bf = cnts > 128;
    if (blockIdx.x == 0) {
        if (t < 32) accum[t] = 0.0f;
        if (t == 0) *flagp = bf;
    }
    long i = (long)blockIdx.x * 256 + t;
    if (i >= CV_TOTAL) return;
    float v;
    if (i < CV_GATW)      v = LD(embW, i, bf);
    else if (i < CV_GATA) v = LD(gatW, i - CV_GATW, bf);
    else if (i < CV_WB)   v = LD(gatA, i - CV_GATA, bf);
    else if (i < CV_GGW)  v = LD(gatWb, i - CV_WB, bf);
    else if (i < CV_GGB)  v = LD(ggW, i - CV_GGW, bf);
    else if (i < CV_DCW1) { long j = i - CV_GGB; v = (j < 3) ? LD(ggb, j, bf) : 0.0f; }
    else if (i < CV_VW1)  v = LD(dcW1, i - CV_DCW1, bf);
    else                  v = LD(vW1, i - CV_VW1, bf);
    out[i] = v;
}

// Both-sides embedding: rows [0, BB*LL) from Xl, rest from Xt. K=54. f32 W.
__global__ void embed_both(const void* __restrict__ Xl, const void* __restrict__ Xt,
                           const float* __restrict__ Wf, float* __restrict__ out,
                           int K, const int* __restrict__ flagp) {
    __shared__ float xrow[DIMD];
    int bf = *flagp;
    int row = blockIdx.x;
    int d = threadIdx.x;
    const void* X; long r;
    if (row < BB * LL) { X = Xl; r = row; }
    else               { X = Xt; r = row - BB * LL; }
    if (d < K) xrow[d] = LD(X, r * K + d, bf);
    __syncthreads();
    float acc = 0.0f;
    for (int k = 0; k < K; ++k)
        acc = fmaf(xrow[k], Wf[(long)k * DIMD + d], acc);
    out[(long)row * DIMD + d] = acc;
}

// Fused [gate of previous layer] + h = x@W + Wb + hA = h@A.
// 4 rows/block, 256 threads = 2 row-groups x 128 cols. All weights f32 (cvw).
// P0/P1 = split-K hp partials of the PREVIOUS layer (unified row space, lig
// rows first). P0 aliases hA: each block reads its own rows before rewriting.
__global__ void gemm_hha_gate(float* __restrict__ X, const float* __restrict__ P0,
                              const float* __restrict__ P1, const float* __restrict__ cvw,
                              int layer, int dogate,
                              float* __restrict__ hout, float* __restrict__ hAout) {
    __shared__ float xs[4][DIMD];
    __shared__ float hs[4][DIMD];
    __shared__ float gred[4][2];
    long row0 = (long)blockIdx.x * 4;
    int d = threadIdx.x & 127, rg = threadIdx.x >> 7;
    int w = threadIdx.x >> 6, lane = threadIdx.x & 63;
    long r0 = row0 + rg * 2, r1 = r0 + 1;
    float xv0 = X[r0 * DIMD + d];
    float xv1 = X[r1 * DIMD + d];
    if (dogate) {
        const float* gW = cvw + CV_GGW + (long)(layer - 1) * 2 * DIMD;
        float gb = cvw[CV_GGB + (layer - 1)];
        float hp0 = fmaxf(P0[r0 * DIMD + d] + P1[r0 * DIMD + d], 0.0f);
        float hp1 = fmaxf(P0[r1 * DIMD + d] + P1[r1 * DIMD + d], 0.0f);
        float s0 = xv0 * gW[d] + hp0 * gW[DIMD + d];
        float s1 = xv1 * gW[d] + hp1 * gW[DIMD + d];
#pragma unroll
        for (int s = 32; s > 0; s >>= 1) { s0 += __shfl_xor(s0, s); s1 += __shfl_xor(s1, s); }
        if (lane == 0) { gred[rg * 2 + 0][w & 1] = s0; gred[rg * 2 + 1][w & 1] = s1; }
        __syncthreads();
        float g0 = gred[rg * 2 + 0][0] + gred[rg * 2 + 0][1] + gb;
        float g1 = gred[rg * 2 + 1][0] + gred[rg * 2 + 1][1] + gb;
        float c0 = 1.0f / (1.0f + expf(-g0));
        float c1 = 1.0f / (1.0f + expf(-g1));
        xv0 = c0 * xv0 + (1.0f - c0) * hp0;
        xv1 = c1 * xv1 + (1.0f - c1) * hp1;
        X[r0 * DIMD + d] = xv0;   // gated x for the next consumer
        X[r1 * DIMD + d] = xv1;
    }
    xs[rg * 2 + 0][d] = xv0;
    xs[rg * 2 + 1][d] = xv1;
    __syncthreads();
    const float* W = cvw + CV_GATW + (long)layer * DIMD * DIMD;
    const float* A = cvw + CV_GATA + (long)layer * DIMD * DIMD;
    float b = cvw[CV_WB + layer * DIMD + d];
    float h0 = b, h1 = b;
    const float* x0 = xs[rg * 2];
    const float* x1 = xs[rg * 2 + 1];
#pragma unroll 8
    for (int k = 0; k < DIMD; ++k) {
        float wv = W[(long)k * DIMD + d];
        h0 = fmaf(x0[k], wv, h0);
        h1 = fmaf(x1[k], wv, h1);
    }
    long ob = r0 * DIMD + d;
    hout[ob] = h0; hout[ob + DIMD] = h1;
    hs[rg * 2][d] = h0; hs[rg * 2 + 1][d] = h1;
    __syncthreads();
    float a0 = 0.0f, a1 = 0.0f;
    const float* g0p = hs[rg * 2];
    const float* g1p = hs[rg * 2 + 1];
#pragma unroll 8
    for (int k = 0; k < DIMD; ++k) {
        float wv = A[(long)k * DIMD + d];
        a0 = fmaf(g0p[k], wv, a0);
        a1 = fmaf(g1p[k], wv, a1);
    }
    hAout[ob] = a0;
    hAout[ob + DIMD] = a1;
}

// e = S1 + S2, S1 = hA·h^T, S2 = h·hA^T (each symmetric-pair-mirrorable).
// blockIdx.y selects the term (halves per-block work, doubles grid).
// Upper-triangle tiles + mirror writes. x: [0,36) target, [36,39) ligand.
__global__ void esym_both(const float* __restrict__ hA_t, const float* __restrict__ h_t,
                          float* __restrict__ e1_t, float* __restrict__ e2_t,
                          const float* __restrict__ hA_l, const float* __restrict__ h_l,
                          float* __restrict__ e1_l, float* __restrict__ e2_l) {
    __shared__ float At[BKT][BMT + 4];
    __shared__ float Bt[BKT][BMT + 4];
    int idx = blockIdx.x, half = blockIdx.y, b = blockIdx.z, t = threadIdx.x;
    const float *hA, *h; float* e; int N;
    if (idx < TGT_TILES) { hA = hA_t; h = h_t; e = half ? e2_t : e1_t; N = TT; }
    else { idx -= TGT_TILES; hA = hA_l; h = h_l; e = half ? e2_l : e1_l; N = LL; }
    int jt = (int)((sqrtf(8.0f * idx + 1.0f) - 1.0f) * 0.5f);
    while ((jt + 1) * (jt + 2) / 2 <= idx) ++jt;
    while (jt * (jt + 1) / 2 > idx) --jt;
    int kt = idx - jt * (jt + 1) / 2;   // kt <= jt
    const float* hAb = hA + (long)b * N * DIMD;
    const float* hb  = h  + (long)b * N * DIMD;
    const float* Ap = half ? hb : hAb;
    const float* Bp = half ? hAb : hb;
    int tm = t & 15, tn = t >> 4;
    int k4 = (t & 7) * 4;
    int row0 = t >> 3;
    float acc[4][4];
#pragma unroll
    for (int i = 0; i < 4; ++i)
#pragma unroll
        for (int jj = 0; jj < 4; ++jj) acc[i][jj] = 0.0f;

#pragma unroll
    for (int c = 0; c < 4; ++c) {
        int ko = c * BKT;
        __syncthreads();
#pragma unroll
        for (int rr = 0; rr < 2; ++rr) {
            int row = row0 + rr * 32;
            float4 av = *(const float4*)&Ap[(long)(jt * BMT + row) * DIMD + ko + k4];
            float4 bv = *(const float4*)&Bp[(long)(kt * BMT + row) * DIMD + ko + k4];
            At[k4 + 0][row] = av.x; At[k4 + 1][row] = av.y;
            At[k4 + 2][row] = av.z; At[k4 + 3][row] = av.w;
            Bt[k4 + 0][row] = bv.x; Bt[k4 + 1][row] = bv.y;
            Bt[k4 + 2][row] = bv.z; Bt[k4 + 3][row] = bv.w;
        }
        __syncthreads();
#pragma unroll
        for (int k = 0; k < BKT; ++k) {
            float4 a4 = *(const float4*)&At[k][tm * 4];
            float4 b4 = *(const float4*)&Bt[k][tn * 4];
            float A[4] = {a4.x, a4.y, a4.z, a4.w};
            float Bv[4] = {b4.x, b4.y, b4.z, b4.w};
#pragma unroll
            for (int i = 0; i < 4; ++i)
#pragma unroll
                for (int jj = 0; jj < 4; ++jj)
                    acc[i][jj] = fmaf(A[i], Bv[jj], acc[i][jj]);
        }
    }
    long ebN = (long)b * N;
    long ebase = (ebN + jt * BMT + tm * 4) * N + kt * BMT + tn * 4;
#pragma unroll
    for (int i = 0; i < 4; ++i) {
        float4 v;
        v.x = acc[i][0]; v.y = acc[i][1]; v.z = acc[i][2]; v.w = acc[i][3];
        *(float4*)&e[ebase + (long)i * N] = v;
    }
    if (jt != kt) {   // mirror (transpose) — sum of halves stays symmetric
        long mbase = (ebN + kt * BMT + tn * 4) * N + jt * BMT + tm * 4;
#pragma unroll
        for (int jj = 0; jj < 4; ++jj) {
            float4 v;
            v.x = acc[0][jj]; v.y = acc[1][jj]; v.z = acc[2][jj]; v.w = acc[3][jj];
            *(float4*)&e[mbase + (long)jj * N] = v;
        }
    }
}

// att row softmax, one WAVE per row. Reads e1+e2, writes normalized att to e1.
template<int CNT>
__device__ __forceinline__ void softmax_row(float* __restrict__ e1row,
                                            const float* __restrict__ e2row,
                                            const void* __restrict__ adj,
                                            long adjbase, int bf) {
    int lane = threadIdx.x & 63;
    float vals[CNT], av[CNT];
    float m = -3.4e38f;
#pragma unroll
    for (int i = 0; i < CNT; ++i) {
        int k = lane + i * 64;
        float a = LD(adj, adjbase + k, bf);
        float v = (a > 0.0f) ? (e1row[k] + e2row[k]) : -9e15f;
        av[i] = a; vals[i] = v;
        m = fmaxf(m, v);
    }
#pragma unroll
    for (int s = 32; s > 0; s >>= 1) m = fmaxf(m, __shfl_xor(m, s));
    float sum = 0.0f;
#pragma unroll
    for (int i = 0; i < CNT; ++i) { vals[i] = expf(vals[i] - m); sum += vals[i]; }
#pragma unroll
    for (int s = 32; s > 0; s >>= 1) sum += __shfl_xor(sum, s);
    float inv = 1.0f / sum;
#pragma unroll
    for (int i = 0; i < CNT; ++i)
        e1row[lane + i * 64] = vals[i] * av[i] * inv;
}

// x < TT/4: target rows; else ligand rows. 4 waves = 4 rows per block.
__global__ void att_softmax_both(float* __restrict__ e1_t, const float* __restrict__ e2_t,
                                 float* __restrict__ e1_l, const float* __restrict__ e2_l,
                                 const void* __restrict__ adj_t, const void* __restrict__ adj_l,
                                 const int* __restrict__ flagp) {
    int bf = *flagp;
    int b = blockIdx.y, x = blockIdx.x;
    int jr = threadIdx.x >> 6;
    if (x < TT / 4) {
        int j = x * 4 + jr;
        long base = ((long)b * TT + j) * TT;
        softmax_row<8>(e1_t + base, e2_t + base, adj_t, base, bf);
    } else {
        int j = (x - TT / 4) * 4 + jr;
        long base = ((long)b * LL + j) * LL;
        softmax_row<2>(e1_l + base, e2_l + base, adj_l, base, bf);
    }
}

// Partial hp GEMM: part[b][j][d] = sum over k-chunk of att[b][j][k]*h[b][k][d]
// BM=32, BN=128, BK=32, 256 threads, 4x4 acc, split-K=2 via blockIdx.y.
// Grid x: [0,16) target row-tiles, [16,20) ligand row-tiles.
__global__ void hp_gemm_both(const float* __restrict__ att_t, const float* __restrict__ h_t,
                             float* __restrict__ p0_t, float* __restrict__ p1_t,
                             const float* __restrict__ att_l, const float* __restrict__ h_l,
                             float* __restrict__ p0_l, float* __restrict__ p1_l) {
    __shared__ float At[32][36];
    __shared__ float Ht[32][DIMD];
    int jt = blockIdx.x, kc = blockIdx.y, b = blockIdx.z;
    int t = threadIdx.x;
    const float *att, *h; float *part0, *part1; int N;
    if (jt < 16) { att = att_t; h = h_t; part0 = p0_t; part1 = p1_t; N = TT; }
    else { jt -= 16; att = att_l; h = h_l; part0 = p0_l; part1 = p1_l; N = LL; }
    const float* attb = att + (long)b * N * N;
    const float* hb = h + (long)b * N * DIMD;
    int tm = t & 7, tn = t >> 3;
    float acc[4][4] = {};
    int kchunk = N / 2;
    int kbeg = kc * kchunk;
    int ar = t >> 3;
    int ac4 = (t & 7) * 4;
    int hk = t >> 5;
    int hc4 = (t & 31) * 4;
    for (int k0 = kbeg; k0 < kbeg + kchunk; k0 += 32) {
        __syncthreads();
        float4 av = *(const float4*)&attb[(long)(jt * 32 + ar) * N + k0 + ac4];
        At[ac4 + 0][ar] = av.x; At[ac4 + 1][ar] = av.y;
        At[ac4 + 2][ar] = av.z; At[ac4 + 3][ar] = av.w;
#pragma unroll
        for (int p = 0; p < 4; ++p)
            *(float4*)&Ht[hk + p * 8][hc4] = *(const float4*)&hb[(long)(k0 + hk + p * 8) * DIMD + hc4];
        __syncthreads();
#pragma unroll
        for (int k = 0; k < 32; ++k) {
            float4 a4 = *(const float4*)&At[k][tm * 4];
            float4 h4 = *(const float4*)&Ht[k][tn * 4];
            float A[4] = {a4.x, a4.y, a4.z, a4.w};
            float H[4] = {h4.x, h4.y, h4.z, h4.w};
#pragma unroll
            for (int i = 0; i < 4; ++i)
#pragma unroll
                for (int jj = 0; jj < 4; ++jj)
                    acc[i][jj] = fmaf(A[i], H[jj], acc[i][jj]);
        }
    }
    float* outp = (kc == 0) ? part0 : part1;
    long obase = ((long)b * N + jt * 32 + tm * 4) * DIMD + tn * 4;
#pragma unroll
    for (int i = 0; i < 4; ++i) {
        float4 v; v.x = acc[i][0]; v.y = acc[i][1]; v.z = acc[i][2]; v.w = acc[i][3];
        *(float4*)&outp[obase + (long)i * DIMD] = v;
    }
}

// Final-layer gate + both pair-MLP projections. blockIdx.y: 0=dc, 1=vdwA.
// Gate (layer 2) computed in-register from P0/P1; x NOT written back (dead).
// outdc = h region (not a gate input); outA = fresh buffer (avoids the race
// of writing over P0 while other blocks still read it).
__global__ void proj_gate(const float* __restrict__ X, const float* __restrict__ P0,
                          const float* __restrict__ P1, const float* __restrict__ cvw,
                          const void* __restrict__ bdc, const void* __restrict__ bA,
                          long rowsplit, float* __restrict__ outdc, float* __restrict__ outA,
                          const int* __restrict__ flagp) {
    __shared__ float xs[4][DIMD];
    __shared__ float gred[4][2];
    int bf = *flagp;
    long row0 = (long)blockIdx.x * 4;
    int d = threadIdx.x & 127, rg = threadIdx.x >> 7;
    int w = threadIdx.x >> 6, lane = threadIdx.x & 63;
    long r0 = row0 + rg * 2, r1 = r0 + 1;
    float xv0 = X[r0 * DIMD + d];
    float xv1 = X[r1 * DIMD + d];
    {
        const float* gW = cvw + CV_GGW + 2L * 2 * DIMD;
        float gb = cvw[CV_GGB + 2];
        float hp0 = fmaxf(P0[r0 * DIMD + d] + P1[r0 * DIMD + d], 0.0f);
        float hp1 = fmaxf(P0[r1 * DIMD + d] + P1[r1 * DIMD + d], 0.0f);
        float s0 = xv0 * gW[d] + hp0 * gW[DIMD + d];
        float s1 = xv1 * gW[d] + hp1 * gW[DIMD + d];
#pragma unroll
        for (int s = 32; s > 0; s >>= 1) { s0 += __shfl_xor(s0, s); s1 += __shfl_xor(s1, s); }
        if (lane == 0) { gred[rg * 2 + 0][w & 1] = s0; gred[rg * 2 + 1][w & 1] = s1; }
        __syncthreads();
        float g0 = gred[rg * 2 + 0][0] + gred[rg * 2 + 0][1] + gb;
        float g1 = gred[rg * 2 + 1][0] + gred[rg * 2 + 1][1] + gb;
        float c0 = 1.0f / (1.0f + expf(-g0));
        float c1 = 1.0f / (1.0f + expf(-g1));
        xv0 = c0 * xv0 + (1.0f - c0) * hp0;
        xv1 = c1 * xv1 + (1.0f - c1) * hp1;
    }
    xs[rg * 2 + 0][d] = xv0;
    xs[rg * 2 + 1][d] = xv1;
    __syncthreads();
    const float* Wf = (blockIdx.y == 0) ? (cvw + CV_DCW1) : (cvw + CV_VW1);
    const void* bias = (blockIdx.y == 0) ? bdc : bA;
    float* out = (blockIdx.y == 0) ? outdc : outA;
    int sideb = row0 >= rowsplit;
    const float* W = Wf + (sideb ? (long)DIMD * DIMD : 0);
    float b0 = sideb ? 0.0f : LD(bias, d, bf);
    float a0 = b0, a1 = b0;
    const float* x0 = xs[rg * 2];
    const float* x1 = xs[rg * 2 + 1];
#pragma unroll 8
    for (int k = 0; k < DIMD; ++k) {
        float wv = W[(long)k * DIMD + d];
        a0 = fmaf(x0[k], wv, a0);
        a1 = fmaf(x1[k], wv, a1);
    }
    long ob = r0 * DIMD + d;
    out[ob] = a0;
    out[ob + DIMD] = a1;
}

// Both transposes in one launch: z<BB -> (in0->out0, b=z), else (in1->out1).
__global__ void transpose_both(const float* __restrict__ in0, float* __restrict__ out0,
                               const float* __restrict__ in1, float* __restrict__ out1) {
    __shared__ float tile[32][33];
    int z = blockIdx.z;
    const float* in; float* outT; int b;
    if (z < BB) { in = in0; outT = out0; b = z; }
    else        { in = in1; outT = out1; b = z - BB; }
    int n0 = blockIdx.x * 32;
    int d0 = blockIdx.y * 32;
    int t = threadIdx.x;
    int tx = t & 31, ty = t >> 5;
    for (int r = ty; r < 32; r += 8)
        tile[r][tx] = in[((long)b * TT + n0 + r) * DIMD + d0 + tx];
    __syncthreads();
    for (int r = ty; r < 32; r += 8)
        outT[((long)b * DIMD + d0 + r) * TT + n0 + tx] = tile[tx][r];
}

// Pair energies. Block = (2 lig rows, tt-half, b). One tt per thread (1024
// blocks -> 4/CU). Target projections transposed [B][128][T], coalesced.
__global__ void pair_energy(const float* __restrict__ ligdc, const float* __restrict__ tgtdcT,
                            const float* __restrict__ ligA, const float* __restrict__ tgtAT,
                            const void* __restrict__ dcW2, const void* __restrict__ dcb2,
                            const void* __restrict__ AW2, const void* __restrict__ Ab2,
                            const void* __restrict__ lpos, const void* __restrict__ tpos,
                            const void* __restrict__ lrad, const void* __restrict__ trad,
                            const void* __restrict__ lval, const void* __restrict__ tval,
                            const void* __restrict__ ii, float* __restrict__ accum,
                            const int* __restrict__ flagp) {
    int bf = *flagp;
    int l0 = blockIdx.x * 2, b = blockIdx.z, t = threadIdx.x;
    int tt = blockIdx.y * 256 + t;
    __shared__ __align__(16) float sdc0[DIMD], sdc1[DIMD], sA0[DIMD], sA1[DIMD];
    __shared__ __align__(16) float w2dc[DIMD], w2A[DIMD];
    __shared__ float red[256];
    if (t < DIMD) {
        sdc0[t] = ligdc[((long)b * LL + l0) * DIMD + t];
        sA0[t]  = ligA [((long)b * LL + l0) * DIMD + t];
        w2dc[t] = LD(dcW2, t, bf);
        w2A[t]  = LD(AW2, t, bf);
    } else {
        int u = t - DIMD;
        sdc1[u] = ligdc[((long)b * LL + l0 + 1) * DIMD + u];
        sA1[u]  = ligA [((long)b * LL + l0 + 1) * DIMD + u];
    }
    __syncthreads();
    const float* tdT = tgtdcT + (long)b * DIMD * TT;
    const float* taT = tgtAT  + (long)b * DIMD * TT;
    float adc0 = 0.0f, adc1 = 0.0f, aA0 = 0.0f, aA1 = 0.0f;
    for (int i4 = 0; i4 < DIMD; i4 += 4) {
#pragma unroll
        for (int j = 0; j < 4; ++j) {
            float td = tdT[(long)(i4 + j) * TT + tt];
            float ta = taT[(long)(i4 + j) * TT + tt];
            float wd = w2dc[i4 + j], wa = w2A[i4 + j];
            adc0 = fmaf(fmaxf(td + sdc0[i4 + j], 0.0f), wd, adc0);
            adc1 = fmaf(fmaxf(td + sdc1[i4 + j], 0.0f), wd, adc1);
            aA0  = fmaf(fmaxf(ta + sA0[i4 + j],  0.0f), wa, aA0);
            aA1  = fmaf(fmaxf(ta + sA1[i4 + j],  0.0f), wa, aA1);
        }
    }
    float lx0 = LD(lpos, ((long)b * LL + l0) * 3 + 0, bf);
    float ly0 = LD(lpos, ((long)b * LL + l0) * 3 + 1, bf);
    float lz0 = LD(lpos, ((long)b * LL + l0) * 3 + 2, bf);
    float lx1 = LD(lpos, ((long)b * LL + l0 + 1) * 3 + 0, bf);
    float ly1 = LD(lpos, ((long)b * LL + l0 + 1) * 3 + 1, bf);
    float lz1 = LD(lpos, ((long)b * LL + l0 + 1) * 3 + 2, bf);
    float lr0 = LD(lrad, (long)b * LL + l0, bf);
    float lr1 = LD(lrad, (long)b * LL + l0 + 1, bf);
    float lv0 = LD(lval, (long)b * LL + l0, bf);
    float lv1 = LD(lval, (long)b * LL + l0 + 1, bf);
    float cdcb2 = LD(dcb2, 0, bf), cab2 = LD(Ab2, 0, bf);
    long iiA0 = ((long)(b * 3 + 0) * LL + l0) * TT;
    long iiB0 = ((long)(b * 3 + 1) * LL + l0) * TT;
    long iiC0 = ((long)(b * 3 + 2) * LL + l0) * TT;
    long iiA1 = iiA0 + TT, iiB1 = iiB0 + TT, iiC1 = iiC0 + TT;
    float tx = LD(tpos, ((long)b * TT + tt) * 3 + 0, bf);
    float ty = LD(tpos, ((long)b * TT + tt) * 3 + 1, bf);
    float tz = LD(tpos, ((long)b * TT + tt) * 3 + 2, bf);
    float tr = LD(trad, (long)b * TT + tt, bf);
    float tv = LD(tval, (long)b * TT + tt, bf);
    float p0 = 0.0f, p1 = 0.0f, p2 = 0.0f, p3 = 0.0f;
#pragma unroll
    for (int li = 0; li < 2; ++li) {
        float dx = (li ? lx1 : lx0) - tx;
        float dy = (li ? ly1 : ly0) - ty;
        float dz = (li ? lz1 : lz0) - tz;
        float dm = sqrtf(dx * dx + dy * dy + dz * dz + 1e-10f);
        if (dm < 0.5f) dm = 1e10f;
        float adcv = li ? adc1 : adc0;
        float aAv  = li ? aA1  : aA0;
        float dev = tanhf(adcv + cdcb2) * 0.2f;
        float vdws = (li ? lr1 : lr0) + tr + dev;
        float dm0 = (vdws < 1e-4f) ? 1.0f : vdws;
        float ratio = dm0 / dm;
        float r2 = ratio * ratio, r6 = r2 * r2 * r2, r12 = r6 * r6;
        float en = fminf(r12 - 2.0f * r6, 100.0f) * (li ? lv1 : lv0) * tv;
        float As = 1.0f / (1.0f + expf(-(aAv + cab2)));
        As = As * (0.0356f - 0.0178f) + 0.0178f;
        p0 = fmaf(As, en, p0);
        float dd = dm - vdws;
        float ramp = fminf(fmaxf(dd * (1.0f / -0.7f), 0.0f), 1.0f);
        p1 = fmaf(ramp, LD(ii, (li ? iiA1 : iiA0) + tt, bf), p1);
        p2 = fmaf(ramp, LD(ii, (li ? iiB1 : iiB0) + tt, bf), p2);
        float ramp2 = fminf(fmaxf(-dd + 1.5f, 0.0f), 1.0f);
        p3 = fmaf(ramp2, LD(ii, (li ? iiC1 : iiC0) + tt, bf), p3);
    }
    for (int e = 0; e < 4; ++e) {
        float v = (e == 0) ? p0 : (e == 1) ? p1 : (e == 2) ? p2 : p3;
        red[t] = v; __syncthreads();
        for (int s = 128; s > 0; s >>= 1) { if (t < s) red[t] += red[t + s]; __syncthreads(); }
        if (t == 0) atomicAdd(&accum[b * 4 + e], red[0]);
        __syncthreads();
    }
}

__global__ void finalize(const float* __restrict__ accum, const void* __restrict__ hb,
                         const void* __restrict__ mc, const void* __restrict__ hyd,
                         const void* __restrict__ rc, const void* __restrict__ rotor,
                         void* __restrict__ out, const int* __restrict__ flagp) {
    int bf = *flagp;
    int t = threadIdx.x;  // 64 threads, use first 32
    if (t >= 32) return;
    int b = t >> 2, e = t & 3;
    float v = accum[t];
    if (e == 1) { float c = LD(hb, 0, bf);  v = -c * c * v; }
    else if (e == 2) { float c = LD(mc, 0, bf);  v = -c * c * v; }
    else if (e == 3) { float c = LD(hyd, 0, bf); v = -c * c * v; }
    float r = LD(rc, 0, bf);
    float den = 1.0f + r * r * LD(rotor, b, bf);
    float res = v / den;
    if (bf) ((bf16*)out)[t] = __float2bfloat16(res);
    else    ((float*)out)[t] = res;
}

extern "C" void kernel_launch(void* const* d_in, const int* in_sizes, int n_in,
                              void* d_out, int out_size, void* d_ws, size_t ws_size,
                              hipStream_t stream) {
    const void* ligand_h = d_in[0];
    const void* target_h = d_in[1];
    const void* ligand_adj = d_in[2];
    const void* target_adj = d_in[3];
    const void* interaction_indice = d_in[4];
    const void* ligand_pos = d_in[5];
    const void* target_pos = d_in[6];
    const void* rotor = d_in[7];
    const void* ligand_vdw = d_in[8];
    const void* target_vdw = d_in[9];
    const void* ligand_valid = d_in[10];
    const void* target_valid = d_in[11];
    const void* emb_W = d_in[12];
    const void* gat_W = d_in[13];
    const void* gat_Wb = d_in[14];
    const void* gat_A = d_in[15];
    const void* gat_gW = d_in[16];
    const void* gat_gb = d_in[17];
    const void* vdwA_W1 = d_in[18];
    const void* vdwA_b1 = d_in[19];
    const void* vdwA_W2 = d_in[20];
    const void* vdwA_b2 = d_in[21];
    const void* dc_W1 = d_in[22];
    const void* dc_b1 = d_in[23];
    const void* dc_W2 = d_in[24];
    const void* dc_b2 = d_in[25];
    const void* hbond_coeff = d_in[26];
    const void* metal_coeff = d_in[27];
    const void* hydrophobic_coeff = d_in[28];
    const void* rotor_coeff = d_in[29];

    float* ws = (float*)d_ws;
    size_t off = 0;
    float* lig_x = ws + off;  off += (size_t)BB * LL * DIMD;   // x unified (lig, tgt)
    float* tgt_x = ws + off;  off += (size_t)BB * TT * DIMD;
    float* h_lig = ws + off;  off += (size_t)BB * LL * DIMD;   // h unified
    float* h_tgt = ws + off;  off += (size_t)BB * TT * DIMD;
    float* hA_lig = ws + off; off += (size_t)BB * LL * DIMD;   // hA unified (= part0)
    float* hA_tgt = ws + off; off += (size_t)BB * TT * DIMD;
    float* accum = ws + off;  off += 32;
    int* flagp = (int*)(ws + off); off += 2;
    float* e_buf = ws + off;  off += (size_t)BB * TT * TT;     // e1 target; later transposes
    float* e_lig = ws + off;  off += (size_t)BB * LL * LL;     // e1 ligand
    float* e2_buf = ws + off; off += (size_t)BB * TT * TT;     // e2 target
    float* e2_lig = ws + off; off += (size_t)BB * LL * LL;     // e2 ligand
    float* part1 = ws + off;  off += (size_t)BB * (LL + TT) * DIMD; // p1 unified (lig first)
    float* projA = ws + off;  off += (size_t)BB * (LL + TT) * DIMD; // vdwA projection out
    float* cvw   = ws + off;  off += (size_t)CV_TOTAL;         // f32 weight copies
    float* part1_l = part1;
    float* part1_t = part1 + (size_t)BB * LL * DIMD;
    float* part0_lig = hA_lig;   // part0 aliases hA (unified row space)
    float* part0_tgt = hA_tgt;
    // pair-MLP projection outputs
    float* ligdc = h_lig;        // dc out reuses h region (rows: lig then tgt)
    float* tgtdc = h_tgt;
    float* ligA = projA;         // vdwA out in fresh buffer (P0 race avoidance)
    float* tgtA = projA + (size_t)BB * LL * DIMD;
    // transposed target projections reuse e_buf (dead after the GAT loop)
    float* tgtdcT = e_buf;
    float* tgtAT  = e_buf + (size_t)BB * DIMD * TT;
    float* wEmb = cvw + CV_EMBW;

    init_cvt<<<(CV_TOTAL + 255) / 256, 256, 0, stream>>>(
        (const unsigned int*)emb_W, emb_W, gat_W, gat_A, gat_Wb,
        gat_gW, gat_gb, dc_W1, vdwA_W1, cvw, accum, flagp);

    // embeddings: x = h @ emb_W (both sides, one launch; out rows contiguous)
    embed_both<<<BB * (LL + TT), DIMD, 0, stream>>>(ligand_h, target_h, wEmb, lig_x, 54, flagp);

    const long ROWSPLIT = (long)BB * LL;   // multiple of 4
    for (int i = 0; i < 3; ++i) {
        // [gate of layer i-1] + h = x@W+Wb ; hA = h@A   (both sides, one launch)
        gemm_hha_gate<<<BB * (LL + TT) / 4, 256, 0, stream>>>(
            lig_x, hA_lig, part1, cvw, i, i > 0 ? 1 : 0, h_lig, hA_lig);
        // e = S1 + S2 (term split over blockIdx.y; symmetric mirror writes)
        esym_both<<<dim3(TGT_TILES + LIG_TILES, 2, BB), 256, 0, stream>>>(
            hA_tgt, h_tgt, e_buf, e2_buf, hA_lig, h_lig, e_lig, e2_lig);
        att_softmax_both<<<dim3(TT / 4 + LL / 4, BB), 256, 0, stream>>>(
            e_buf, e2_buf, e_lig, e2_lig, target_adj, ligand_adj, flagp);
        hp_gemm_both<<<dim3(20, 2, BB), 256, 0, stream>>>(
            e_buf, h_tgt, part0_tgt, part1_t, e_lig, h_lig, part0_lig, part1_l);
    }

    // final gate (layer 2) + both pair-MLP projections in one launch
    proj_gate<<<dim3(BB * (LL + TT) / 4, 2), 256, 0, stream>>>(
        lig_x, hA_lig, part1, cvw, dc_b1, vdwA_b1, ROWSPLIT, ligdc, ligA, flagp);

    // transpose target projections for coalesced pair_energy reads (one launch)
    transpose_both<<<dim3(TT / 32, DIMD / 32, 2 * BB), 256, 0, stream>>>(
        tgtdc, tgtdcT, tgtA, tgtAT);

    pair_energy<<<dim3(LL / 2, 2, BB), 256, 0, stream>>>(
        ligdc, tgtdcT, ligA, tgtAT, dc_W2, dc_b2, vdwA_W2, vdwA_b2,
        ligand_pos, target_pos, ligand_vdw, target_vdw,
        ligand_valid, target_valid, interaction_indice, accum, flagp);

    finalize<<<1, 64, 0, stream>>>(accum, hbond_coeff, metal_coeff,
                                   hydrophobic_coeff, rotor_coeff, rotor, d_out, flagp);
}

// Round 9
// 341.888 us; speedup vs baseline: 1.6184x; 1.1244x over previous
//
#include <hip/hip_runtime.h>
#include <hip/hip_bf16.h>
#include <math.h>

typedef __hip_bfloat16 bf16;

#define DIMD 128
#define BB 8
#define LL 128
#define TT 512

// esym tile params
#define BMT 64
#define BKT 32
#define TGT_TILES 36   // 8*9/2 upper-tri tiles (N=512 / 64)
#define LIG_TILES 3    // 2*3/2 upper-tri tiles (N=128 / 64)

// cvt'd f32 weight region element offsets
#define CV_EMBW   0L
#define CV_GATW   (CV_EMBW + 54 * 128)
#define CV_GATA   (CV_GATW + 3 * 128 * 128)
#define CV_WB     (CV_GATA + 3 * 128 * 128)
#define CV_GGW    (CV_WB + 3 * 128)
#define CV_GGB    (CV_GGW + 3 * 2 * 128)
#define CV_DCW1   (CV_GGB + 4)
#define CV_VW1    (CV_DCW1 + 2 * 128 * 128)
#define CV_TOTAL  (CV_VW1 + 2 * 128 * 128)

// Runtime-dtype load of external inputs: bf==1 -> bf16, else f32.
__device__ __forceinline__ float LD(const void* p, long i, int bf) {
    if (bf) return __bfloat162float(((const bf16*)p)[i]);
    return ((const float*)p)[i];
}

// One-time: detect dtype (self-detect per block), zero accum, publish flagp,
// convert hot weights to f32 (branch-free GEMMs afterwards).
__global__ void init_cvt(const unsigned int* __restrict__ embw_raw,
                         const void* __restrict__ embW, const void* __restrict__ gatW,
                         const void* __restrict__ gatA, const void* __restrict__ gatWb,
                         const void* __restrict__ ggW, const void* __restrict__ ggb,
                         const void* __restrict__ dcW1, const void* __restrict__ vW1,
                         float* __restrict__ out, float* __restrict__ accum,
                         int* __restrict__ flagp) {
    __shared__ int cnts;
    int t = threadIdx.x;
    if (t == 0) cnts = 0;
    __syncthreads();
    unsigned int bword = (embw_raw[t] >> 8) & 0xffu;
    unsigned int e = bword & 0x7fu;
    if (e >= 0x38u && e <= 0x3fu) atomicAdd(&cnts, 1);
    __syncthreads();
    int bf = cnts > 128;
    if (blockIdx.x == 0) {
        if (t < 32) accum[t] = 0.0f;
        if (t == 0) *flagp = bf;
    }
    long i = (long)blockIdx.x * 256 + t;
    if (i >= CV_TOTAL) return;
    float v;
    if (i < CV_GATW)      v = LD(embW, i, bf);
    else if (i < CV_GATA) v = LD(gatW, i - CV_GATW, bf);
    else if (i < CV_WB)   v = LD(gatA, i - CV_GATA, bf);
    else if (i < CV_GGW)  v = LD(gatWb, i - CV_WB, bf);
    else if (i < CV_GGB)  v = LD(ggW, i - CV_GGW, bf);
    else if (i < CV_DCW1) { long j = i - CV_GGB; v = (j < 3) ? LD(ggb, j, bf) : 0.0f; }
    else if (i < CV_VW1)  v = LD(dcW1, i - CV_DCW1, bf);
    else                  v = LD(vW1, i - CV_VW1, bf);
    out[i] = v;
}

// Both-sides embedding: rows [0, BB*LL) from Xl, rest from Xt. K=54. f32 W.
__global__ void embed_both(const void* __restrict__ Xl, const void* __restrict__ Xt,
                           const float* __restrict__ Wf, float* __restrict__ out,
                           int K, const int* __restrict__ flagp) {
    __shared__ float xrow[DIMD];
    int bf = *flagp;
    int row = blockIdx.x;
    int d = threadIdx.x;
    const void* X; long r;
    if (row < BB * LL) { X = Xl; r = row; }
    else               { X = Xt; r = row - BB * LL; }
    if (d < K) xrow[d] = LD(X, r * K + d, bf);
    __syncthreads();
    float acc = 0.0f;
    for (int k = 0; k < K; ++k)
        acc = fmaf(xrow[k], Wf[(long)k * DIMD + d], acc);
    out[(long)row * DIMD + d] = acc;
}

// Fused [gate of previous layer] + h = x@W + Wb + hA = h@A.
// 4 rows/block, 256 threads. P0..P3 = split-K hp partials of the previous
// layer (unified row space, lig rows first). P0 aliases hA: each block reads
// its own rows before rewriting them.
__global__ void gemm_hha_gate(float* __restrict__ X, const float* __restrict__ P0,
                              const float* __restrict__ P1, const float* __restrict__ P2,
                              const float* __restrict__ P3, const float* __restrict__ cvw,
                              int layer, int dogate,
                              float* __restrict__ hout, float* __restrict__ hAout) {
    __shared__ float xs[4][DIMD];
    __shared__ float hs[4][DIMD];
    __shared__ float gred[4][2];
    long row0 = (long)blockIdx.x * 4;
    int d = threadIdx.x & 127, rg = threadIdx.x >> 7;
    int w = threadIdx.x >> 6, lane = threadIdx.x & 63;
    long r0 = row0 + rg * 2, r1 = r0 + 1;
    float xv0 = X[r0 * DIMD + d];
    float xv1 = X[r1 * DIMD + d];
    if (dogate) {
        const float* gW = cvw + CV_GGW + (long)(layer - 1) * 2 * DIMD;
        float gb = cvw[CV_GGB + (layer - 1)];
        float hp0 = fmaxf(P0[r0 * DIMD + d] + P1[r0 * DIMD + d]
                        + P2[r0 * DIMD + d] + P3[r0 * DIMD + d], 0.0f);
        float hp1 = fmaxf(P0[r1 * DIMD + d] + P1[r1 * DIMD + d]
                        + P2[r1 * DIMD + d] + P3[r1 * DIMD + d], 0.0f);
        float s0 = xv0 * gW[d] + hp0 * gW[DIMD + d];
        float s1 = xv1 * gW[d] + hp1 * gW[DIMD + d];
#pragma unroll
        for (int s = 32; s > 0; s >>= 1) { s0 += __shfl_xor(s0, s); s1 += __shfl_xor(s1, s); }
        if (lane == 0) { gred[rg * 2 + 0][w & 1] = s0; gred[rg * 2 + 1][w & 1] = s1; }
        __syncthreads();
        float g0 = gred[rg * 2 + 0][0] + gred[rg * 2 + 0][1] + gb;
        float g1 = gred[rg * 2 + 1][0] + gred[rg * 2 + 1][1] + gb;
        float c0 = 1.0f / (1.0f + expf(-g0));
        float c1 = 1.0f / (1.0f + expf(-g1));
        xv0 = c0 * xv0 + (1.0f - c0) * hp0;
        xv1 = c1 * xv1 + (1.0f - c1) * hp1;
        X[r0 * DIMD + d] = xv0;   // gated x for the next consumer
        X[r1 * DIMD + d] = xv1;
    }
    xs[rg * 2 + 0][d] = xv0;
    xs[rg * 2 + 1][d] = xv1;
    __syncthreads();
    const float* W = cvw + CV_GATW + (long)layer * DIMD * DIMD;
    const float* A = cvw + CV_GATA + (long)layer * DIMD * DIMD;
    float b = cvw[CV_WB + layer * DIMD + d];
    float h0 = b, h1 = b;
    const float* x0 = xs[rg * 2];
    const float* x1 = xs[rg * 2 + 1];
#pragma unroll 8
    for (int k = 0; k < DIMD; ++k) {
        float wv = W[(long)k * DIMD + d];
        h0 = fmaf(x0[k], wv, h0);
        h1 = fmaf(x1[k], wv, h1);
    }
    long ob = r0 * DIMD + d;
    hout[ob] = h0; hout[ob + DIMD] = h1;
    hs[rg * 2][d] = h0; hs[rg * 2 + 1][d] = h1;
    __syncthreads();
    float a0 = 0.0f, a1 = 0.0f;
    const float* g0p = hs[rg * 2];
    const float* g1p = hs[rg * 2 + 1];
#pragma unroll 8
    for (int k = 0; k < DIMD; ++k) {
        float wv = A[(long)k * DIMD + d];
        a0 = fmaf(g0p[k], wv, a0);
        a1 = fmaf(g1p[k], wv, a1);
    }
    hAout[ob] = a0;
    hAout[ob + DIMD] = a1;
}

// e = S1 + S2, S1 = hA·h^T, S2 = h·hA^T (each symmetric-pair-mirrorable).
// blockIdx.y selects the term. Upper-triangle tiles + mirror writes.
__global__ void esym_both(const float* __restrict__ hA_t, const float* __restrict__ h_t,
                          float* __restrict__ e1_t, float* __restrict__ e2_t,
                          const float* __restrict__ hA_l, const float* __restrict__ h_l,
                          float* __restrict__ e1_l, float* __restrict__ e2_l) {
    __shared__ float At[BKT][BMT + 4];
    __shared__ float Bt[BKT][BMT + 4];
    int idx = blockIdx.x, half = blockIdx.y, b = blockIdx.z, t = threadIdx.x;
    const float *hA, *h; float* e; int N;
    if (idx < TGT_TILES) { hA = hA_t; h = h_t; e = half ? e2_t : e1_t; N = TT; }
    else { idx -= TGT_TILES; hA = hA_l; h = h_l; e = half ? e2_l : e1_l; N = LL; }
    int jt = (int)((sqrtf(8.0f * idx + 1.0f) - 1.0f) * 0.5f);
    while ((jt + 1) * (jt + 2) / 2 <= idx) ++jt;
    while (jt * (jt + 1) / 2 > idx) --jt;
    int kt = idx - jt * (jt + 1) / 2;   // kt <= jt
    const float* hAb = hA + (long)b * N * DIMD;
    const float* hb  = h  + (long)b * N * DIMD;
    const float* Ap = half ? hb : hAb;
    const float* Bp = half ? hAb : hb;
    int tm = t & 15, tn = t >> 4;
    int k4 = (t & 7) * 4;
    int row0 = t >> 3;
    float acc[4][4];
#pragma unroll
    for (int i = 0; i < 4; ++i)
#pragma unroll
        for (int jj = 0; jj < 4; ++jj) acc[i][jj] = 0.0f;

#pragma unroll
    for (int c = 0; c < 4; ++c) {
        int ko = c * BKT;
        __syncthreads();
#pragma unroll
        for (int rr = 0; rr < 2; ++rr) {
            int row = row0 + rr * 32;
            float4 av = *(const float4*)&Ap[(long)(jt * BMT + row) * DIMD + ko + k4];
            float4 bv = *(const float4*)&Bp[(long)(kt * BMT + row) * DIMD + ko + k4];
            At[k4 + 0][row] = av.x; At[k4 + 1][row] = av.y;
            At[k4 + 2][row] = av.z; At[k4 + 3][row] = av.w;
            Bt[k4 + 0][row] = bv.x; Bt[k4 + 1][row] = bv.y;
            Bt[k4 + 2][row] = bv.z; Bt[k4 + 3][row] = bv.w;
        }
        __syncthreads();
#pragma unroll
        for (int k = 0; k < BKT; ++k) {
            float4 a4 = *(const float4*)&At[k][tm * 4];
            float4 b4 = *(const float4*)&Bt[k][tn * 4];
            float A[4] = {a4.x, a4.y, a4.z, a4.w};
            float Bv[4] = {b4.x, b4.y, b4.z, b4.w};
#pragma unroll
            for (int i = 0; i < 4; ++i)
#pragma unroll
                for (int jj = 0; jj < 4; ++jj)
                    acc[i][jj] = fmaf(A[i], Bv[jj], acc[i][jj]);
        }
    }
    long ebN = (long)b * N;
    long ebase = (ebN + jt * BMT + tm * 4) * N + kt * BMT + tn * 4;
#pragma unroll
    for (int i = 0; i < 4; ++i) {
        float4 v;
        v.x = acc[i][0]; v.y = acc[i][1]; v.z = acc[i][2]; v.w = acc[i][3];
        *(float4*)&e[ebase + (long)i * N] = v;
    }
    if (jt != kt) {   // mirror (transpose) — sum of halves stays symmetric
        long mbase = (ebN + kt * BMT + tn * 4) * N + jt * BMT + tm * 4;
#pragma unroll
        for (int jj = 0; jj < 4; ++jj) {
            float4 v;
            v.x = acc[0][jj]; v.y = acc[1][jj]; v.z = acc[2][jj]; v.w = acc[3][jj];
            *(float4*)&e[mbase + (long)jj * N] = v;
        }
    }
}

// att row softmax, one WAVE per row. Reads e1+e2, writes normalized att to e1.
template<int CNT>
__device__ __forceinline__ void softmax_row(float* __restrict__ e1row,
                                            const float* __restrict__ e2row,
                                            const void* __restrict__ adj,
                                            long adjbase, int bf) {
    int lane = threadIdx.x & 63;
    float vals[CNT], av[CNT];
    float m = -3.4e38f;
#pragma unroll
    for (int i = 0; i < CNT; ++i) {
        int k = lane + i * 64;
        float a = LD(adj, adjbase + k, bf);
        float v = (a > 0.0f) ? (e1row[k] + e2row[k]) : -9e15f;
        av[i] = a; vals[i] = v;
        m = fmaxf(m, v);
    }
#pragma unroll
    for (int s = 32; s > 0; s >>= 1) m = fmaxf(m, __shfl_xor(m, s));
    float sum = 0.0f;
#pragma unroll
    for (int i = 0; i < CNT; ++i) { vals[i] = expf(vals[i] - m); sum += vals[i]; }
#pragma unroll
    for (int s = 32; s > 0; s >>= 1) sum += __shfl_xor(sum, s);
    float inv = 1.0f / sum;
#pragma unroll
    for (int i = 0; i < CNT; ++i)
        e1row[lane + i * 64] = vals[i] * av[i] * inv;
}

// x < TT/4: target rows; else ligand rows. 4 waves = 4 rows per block.
__global__ void att_softmax_both(float* __restrict__ e1_t, const float* __restrict__ e2_t,
                                 float* __restrict__ e1_l, const float* __restrict__ e2_l,
                                 const void* __restrict__ adj_t, const void* __restrict__ adj_l,
                                 const int* __restrict__ flagp) {
    int bf = *flagp;
    int b = blockIdx.y, x = blockIdx.x;
    int jr = threadIdx.x >> 6;
    if (x < TT / 4) {
        int j = x * 4 + jr;
        long base = ((long)b * TT + j) * TT;
        softmax_row<8>(e1_t + base, e2_t + base, adj_t, base, bf);
    } else {
        int j = (x - TT / 4) * 4 + jr;
        long base = ((long)b * LL + j) * LL;
        softmax_row<2>(e1_l + base, e2_l + base, adj_l, base, bf);
    }
}

// Partial hp GEMM: P[kc][row][d] = sum over k-quarter of att[j][k]*h[k][d]
// BM=32, BN=128, BK=32, 256 threads, 4x4 acc, split-K=4 via blockIdx.y.
// Grid x: [0,16) target row-tiles, [16,20) ligand row-tiles.
// P0..P3 are UNIFIED row-space bases (lig rows first, then tgt).
__global__ void hp_gemm_both(const float* __restrict__ att_t, const float* __restrict__ h_t,
                             const float* __restrict__ att_l, const float* __restrict__ h_l,
                             float* __restrict__ P0, float* __restrict__ P1,
                             float* __restrict__ P2, float* __restrict__ P3) {
    __shared__ float At[32][36];
    __shared__ float Ht[32][DIMD];
    int jt = blockIdx.x, kc = blockIdx.y, b = blockIdx.z;
    int t = threadIdx.x;
    const float *att, *h; int N; long rowbase;
    if (jt < 16) { att = att_t; h = h_t; N = TT; rowbase = (long)BB * LL + (long)b * TT; }
    else { jt -= 16; att = att_l; h = h_l; N = LL; rowbase = (long)b * LL; }
    const float* attb = att + (long)b * N * N;
    const float* hb = h + (long)b * N * DIMD;
    int tm = t & 7, tn = t >> 3;
    float acc[4][4] = {};
    int kchunk = N / 4;
    int kbeg = kc * kchunk;
    int ar = t >> 3;
    int ac4 = (t & 7) * 4;
    int hk = t >> 5;
    int hc4 = (t & 31) * 4;
    for (int k0 = kbeg; k0 < kbeg + kchunk; k0 += 32) {
        __syncthreads();
        float4 av = *(const float4*)&attb[(long)(jt * 32 + ar) * N + k0 + ac4];
        At[ac4 + 0][ar] = av.x; At[ac4 + 1][ar] = av.y;
        At[ac4 + 2][ar] = av.z; At[ac4 + 3][ar] = av.w;
#pragma unroll
        for (int p = 0; p < 4; ++p)
            *(float4*)&Ht[hk + p * 8][hc4] = *(const float4*)&hb[(long)(k0 + hk + p * 8) * DIMD + hc4];
        __syncthreads();
#pragma unroll
        for (int k = 0; k < 32; ++k) {
            float4 a4 = *(const float4*)&At[k][tm * 4];
            float4 h4 = *(const float4*)&Ht[k][tn * 4];
            float A[4] = {a4.x, a4.y, a4.z, a4.w};
            float H[4] = {h4.x, h4.y, h4.z, h4.w};
#pragma unroll
            for (int i = 0; i < 4; ++i)
#pragma unroll
                for (int jj = 0; jj < 4; ++jj)
                    acc[i][jj] = fmaf(A[i], H[jj], acc[i][jj]);
        }
    }
    float* outp = (kc == 0) ? P0 : (kc == 1) ? P1 : (kc == 2) ? P2 : P3;
    long obase = (rowbase + jt * 32 + tm * 4) * DIMD + tn * 4;
#pragma unroll
    for (int i = 0; i < 4; ++i) {
        float4 v; v.x = acc[i][0]; v.y = acc[i][1]; v.z = acc[i][2]; v.w = acc[i][3];
        *(float4*)&outp[obase + (long)i * DIMD] = v;
    }
}

// Final-layer gate + both pair-MLP projections. blockIdx.y: 0=dc, 1=vdwA.
__global__ void proj_gate(const float* __restrict__ X, const float* __restrict__ P0,
                          const float* __restrict__ P1, const float* __restrict__ P2,
                          const float* __restrict__ P3, const float* __restrict__ cvw,
                          const void* __restrict__ bdc, const void* __restrict__ bA,
                          long rowsplit, float* __restrict__ outdc, float* __restrict__ outA,
                          const int* __restrict__ flagp) {
    __shared__ float xs[4][DIMD];
    __shared__ float gred[4][2];
    int bf = *flagp;
    long row0 = (long)blockIdx.x * 4;
    int d = threadIdx.x & 127, rg = threadIdx.x >> 7;
    int w = threadIdx.x >> 6, lane = threadIdx.x & 63;
    long r0 = row0 + rg * 2, r1 = r0 + 1;
    float xv0 = X[r0 * DIMD + d];
    float xv1 = X[r1 * DIMD + d];
    {
        const float* gW = cvw + CV_GGW + 2L * 2 * DIMD;
        float gb = cvw[CV_GGB + 2];
        float hp0 = fmaxf(P0[r0 * DIMD + d] + P1[r0 * DIMD + d]
                        + P2[r0 * DIMD + d] + P3[r0 * DIMD + d], 0.0f);
        float hp1 = fmaxf(P0[r1 * DIMD + d] + P1[r1 * DIMD + d]
                        + P2[r1 * DIMD + d] + P3[r1 * DIMD + d], 0.0f);
        float s0 = xv0 * gW[d] + hp0 * gW[DIMD + d];
        float s1 = xv1 * gW[d] + hp1 * gW[DIMD + d];
#pragma unroll
        for (int s = 32; s > 0; s >>= 1) { s0 += __shfl_xor(s0, s); s1 += __shfl_xor(s1, s); }
        if (lane == 0) { gred[rg * 2 + 0][w & 1] = s0; gred[rg * 2 + 1][w & 1] = s1; }
        __syncthreads();
        float g0 = gred[rg * 2 + 0][0] + gred[rg * 2 + 0][1] + gb;
        float g1 = gred[rg * 2 + 1][0] + gred[rg * 2 + 1][1] + gb;
        float c0 = 1.0f / (1.0f + expf(-g0));
        float c1 = 1.0f / (1.0f + expf(-g1));
        xv0 = c0 * xv0 + (1.0f - c0) * hp0;
        xv1 = c1 * xv1 + (1.0f - c1) * hp1;
    }
    xs[rg * 2 + 0][d] = xv0;
    xs[rg * 2 + 1][d] = xv1;
    __syncthreads();
    const float* Wf = (blockIdx.y == 0) ? (cvw + CV_DCW1) : (cvw + CV_VW1);
    const void* bias = (blockIdx.y == 0) ? bdc : bA;
    float* out = (blockIdx.y == 0) ? outdc : outA;
    int sideb = row0 >= rowsplit;
    const float* W = Wf + (sideb ? (long)DIMD * DIMD : 0);
    float b0 = sideb ? 0.0f : LD(bias, d, bf);
    float a0 = b0, a1 = b0;
    const float* x0 = xs[rg * 2];
    const float* x1 = xs[rg * 2 + 1];
#pragma unroll 8
    for (int k = 0; k < DIMD; ++k) {
        float wv = W[(long)k * DIMD + d];
        a0 = fmaf(x0[k], wv, a0);
        a1 = fmaf(x1[k], wv, a1);
    }
    long ob = r0 * DIMD + d;
    out[ob] = a0;
    out[ob + DIMD] = a1;
}

// Both transposes in one launch: z<BB -> (in0->out0, b=z), else (in1->out1).
__global__ void transpose_both(const float* __restrict__ in0, float* __restrict__ out0,
                               const float* __restrict__ in1, float* __restrict__ out1) {
    __shared__ float tile[32][33];
    int z = blockIdx.z;
    const float* in; float* outT; int b;
    if (z < BB) { in = in0; outT = out0; b = z; }
    else        { in = in1; outT = out1; b = z - BB; }
    int n0 = blockIdx.x * 32;
    int d0 = blockIdx.y * 32;
    int t = threadIdx.x;
    int tx = t & 31, ty = t >> 5;
    for (int r = ty; r < 32; r += 8)
        tile[r][tx] = in[((long)b * TT + n0 + r) * DIMD + d0 + tx];
    __syncthreads();
    for (int r = ty; r < 32; r += 8)
        outT[((long)b * DIMD + d0 + r) * TT + n0 + tx] = tile[tx][r];
}

// Pair energies. Block = (b, 2 ligand rows); lane handles tt = 2t, 2t+1.
// All end-phase scalars (tpos/trad/tval/ii) PREFETCHED before the dot loop so
// their HBM latency hides under the 128-iter L2-bound MLP dot phase.
__global__ void pair_energy(const float* __restrict__ ligdc, const float* __restrict__ tgtdcT,
                            const float* __restrict__ ligA, const float* __restrict__ tgtAT,
                            const void* __restrict__ dcW2, const void* __restrict__ dcb2,
                            const void* __restrict__ AW2, const void* __restrict__ Ab2,
                            const void* __restrict__ lpos, const void* __restrict__ tpos,
                            const void* __restrict__ lrad, const void* __restrict__ trad,
                            const void* __restrict__ lval, const void* __restrict__ tval,
                            const void* __restrict__ ii, float* __restrict__ accum,
                            const int* __restrict__ flagp) {
    int bf = *flagp;
    int l0 = blockIdx.x * 2, b = blockIdx.y, t = threadIdx.x;
    __shared__ __align__(16) float sdc0[DIMD], sdc1[DIMD], sA0[DIMD], sA1[DIMD];
    __shared__ __align__(16) float w2dc[DIMD], w2A[DIMD];
    __shared__ float redw[4][4];
    if (t < DIMD) {
        sdc0[t] = ligdc[((long)b * LL + l0) * DIMD + t];
        sA0[t]  = ligA [((long)b * LL + l0) * DIMD + t];
        w2dc[t] = LD(dcW2, t, bf);
        w2A[t]  = LD(AW2, t, bf);
    } else {
        int u = t - DIMD;
        sdc1[u] = ligdc[((long)b * LL + l0 + 1) * DIMD + u];
        sA1[u]  = ligA [((long)b * LL + l0 + 1) * DIMD + u];
    }
    int tt0 = t * 2;
    // ---- prefetch (issued before the dot loop; consumed after it) ----
    float tx0 = LD(tpos, ((long)b * TT + tt0) * 3 + 0, bf);
    float ty0 = LD(tpos, ((long)b * TT + tt0) * 3 + 1, bf);
    float tz0 = LD(tpos, ((long)b * TT + tt0) * 3 + 2, bf);
    float tx1 = LD(tpos, ((long)b * TT + tt0 + 1) * 3 + 0, bf);
    float ty1 = LD(tpos, ((long)b * TT + tt0 + 1) * 3 + 1, bf);
    float tz1 = LD(tpos, ((long)b * TT + tt0 + 1) * 3 + 2, bf);
    float tr0 = LD(trad, (long)b * TT + tt0, bf);
    float tr1 = LD(trad, (long)b * TT + tt0 + 1, bf);
    float tv0 = LD(tval, (long)b * TT + tt0, bf);
    float tv1 = LD(tval, (long)b * TT + tt0 + 1, bf);
    long iiA0 = ((long)(b * 3 + 0) * LL + l0) * TT;
    long iiB0 = ((long)(b * 3 + 1) * LL + l0) * TT;
    long iiC0 = ((long)(b * 3 + 2) * LL + l0) * TT;
    long iiA1 = iiA0 + TT, iiB1 = iiB0 + TT, iiC1 = iiC0 + TT;
    float iA00 = LD(ii, iiA0 + tt0, bf), iA01 = LD(ii, iiA0 + tt0 + 1, bf);
    float iA10 = LD(ii, iiA1 + tt0, bf), iA11 = LD(ii, iiA1 + tt0 + 1, bf);
    float iB00 = LD(ii, iiB0 + tt0, bf), iB01 = LD(ii, iiB0 + tt0 + 1, bf);
    float iB10 = LD(ii, iiB1 + tt0, bf), iB11 = LD(ii, iiB1 + tt0 + 1, bf);
    float iC00 = LD(ii, iiC0 + tt0, bf), iC01 = LD(ii, iiC0 + tt0 + 1, bf);
    float iC10 = LD(ii, iiC1 + tt0, bf), iC11 = LD(ii, iiC1 + tt0 + 1, bf);
    float lx0 = LD(lpos, ((long)b * LL + l0) * 3 + 0, bf);
    float ly0 = LD(lpos, ((long)b * LL + l0) * 3 + 1, bf);
    float lz0 = LD(lpos, ((long)b * LL + l0) * 3 + 2, bf);
    float lx1 = LD(lpos, ((long)b * LL + l0 + 1) * 3 + 0, bf);
    float ly1 = LD(lpos, ((long)b * LL + l0 + 1) * 3 + 1, bf);
    float lz1 = LD(lpos, ((long)b * LL + l0 + 1) * 3 + 2, bf);
    float lr0 = LD(lrad, (long)b * LL + l0, bf);
    float lr1 = LD(lrad, (long)b * LL + l0 + 1, bf);
    float lv0 = LD(lval, (long)b * LL + l0, bf);
    float lv1 = LD(lval, (long)b * LL + l0 + 1, bf);
    float cdcb2 = LD(dcb2, 0, bf), cab2 = LD(Ab2, 0, bf);
    __syncthreads();
    // ---- MLP dot loop (L2-bound; hides the prefetch latency) ----
    const float* tdT = tgtdcT + (long)b * DIMD * TT;
    const float* taT = tgtAT  + (long)b * DIMD * TT;
    float adc00 = 0.0f, adc01 = 0.0f, adc10 = 0.0f, adc11 = 0.0f;
    float aA00 = 0.0f, aA01 = 0.0f, aA10 = 0.0f, aA11 = 0.0f;
    for (int i4 = 0; i4 < DIMD; i4 += 4) {
        float4 wd = *(const float4*)&w2dc[i4];
        float4 wa = *(const float4*)&w2A[i4];
        float4 v0d = *(const float4*)&sdc0[i4];
        float4 v1d = *(const float4*)&sdc1[i4];
        float4 v0a = *(const float4*)&sA0[i4];
        float4 v1a = *(const float4*)&sA1[i4];
        float wdv[4] = {wd.x, wd.y, wd.z, wd.w};
        float wav[4] = {wa.x, wa.y, wa.z, wa.w};
        float s0d[4] = {v0d.x, v0d.y, v0d.z, v0d.w};
        float s1d[4] = {v1d.x, v1d.y, v1d.z, v1d.w};
        float s0a[4] = {v0a.x, v0a.y, v0a.z, v0a.w};
        float s1a[4] = {v1a.x, v1a.y, v1a.z, v1a.w};
#pragma unroll
        for (int j = 0; j < 4; ++j) {
            float2 td = *(const float2*)&tdT[(long)(i4 + j) * TT + tt0];
            float2 ta = *(const float2*)&taT[(long)(i4 + j) * TT + tt0];
            adc00 = fmaf(fmaxf(td.x + s0d[j], 0.0f), wdv[j], adc00);
            adc01 = fmaf(fmaxf(td.y + s0d[j], 0.0f), wdv[j], adc01);
            adc10 = fmaf(fmaxf(td.x + s1d[j], 0.0f), wdv[j], adc10);
            adc11 = fmaf(fmaxf(td.y + s1d[j], 0.0f), wdv[j], adc11);
            aA00 = fmaf(fmaxf(ta.x + s0a[j], 0.0f), wav[j], aA00);
            aA01 = fmaf(fmaxf(ta.y + s0a[j], 0.0f), wav[j], aA01);
            aA10 = fmaf(fmaxf(ta.x + s1a[j], 0.0f), wav[j], aA10);
            aA11 = fmaf(fmaxf(ta.y + s1a[j], 0.0f), wav[j], aA11);
        }
    }
    // ---- energies (all inputs already in registers) ----
    float p0 = 0.0f, p1 = 0.0f, p2 = 0.0f, p3 = 0.0f;
#pragma unroll
    for (int jj = 0; jj < 2; ++jj) {
        float tx = jj ? tx1 : tx0, ty = jj ? ty1 : ty0, tz = jj ? tz1 : tz0;
        float tr = jj ? tr1 : tr0, tv = jj ? tv1 : tv0;
#pragma unroll
        for (int li = 0; li < 2; ++li) {
            float dx = (li ? lx1 : lx0) - tx;
            float dy = (li ? ly1 : ly0) - ty;
            float dz = (li ? lz1 : lz0) - tz;
            float dm = sqrtf(dx * dx + dy * dy + dz * dz + 1e-10f);
            if (dm < 0.5f) dm = 1e10f;
            float adcv = jj ? (li ? adc11 : adc01) : (li ? adc10 : adc00);
            float aAv  = jj ? (li ? aA11  : aA01)  : (li ? aA10  : aA00);
            float dev = tanhf(adcv + cdcb2) * 0.2f;
            float vdws = (li ? lr1 : lr0) + tr + dev;
            float dm0 = (vdws < 1e-4f) ? 1.0f : vdws;
            float ratio = dm0 / dm;
            float r2 = ratio * ratio, r6 = r2 * r2 * r2, r12 = r6 * r6;
            float en = fminf(r12 - 2.0f * r6, 100.0f) * (li ? lv1 : lv0) * tv;
            float As = 1.0f / (1.0f + expf(-(aAv + cab2)));
            As = As * (0.0356f - 0.0178f) + 0.0178f;
            p0 = fmaf(As, en, p0);
            float dd = dm - vdws;
            float ramp = fminf(fmaxf(dd * (1.0f / -0.7f), 0.0f), 1.0f);
            float ramp2 = fminf(fmaxf(-dd + 1.5f, 0.0f), 1.0f);
            float vA = jj ? (li ? iA11 : iA01) : (li ? iA10 : iA00);
            float vB = jj ? (li ? iB11 : iB01) : (li ? iB10 : iB00);
            float vC = jj ? (li ? iC11 : iC01) : (li ? iC10 : iC00);
            p1 = fmaf(ramp, vA, p1);
            p2 = fmaf(ramp, vB, p2);
            p3 = fmaf(ramp2, vC, p3);
        }
    }
    // ---- reduction: wave shfl -> 4x4 LDS -> atomics (2 barriers total) ----
#pragma unroll
    for (int s = 32; s > 0; s >>= 1) {
        p0 += __shfl_xor(p0, s);
        p1 += __shfl_xor(p1, s);
        p2 += __shfl_xor(p2, s);
        p3 += __shfl_xor(p3, s);
    }
    int w = t >> 6, lane = t & 63;
    if (lane == 0) { redw[w][0] = p0; redw[w][1] = p1; redw[w][2] = p2; redw[w][3] = p3; }
    __syncthreads();
    if (t < 4) {
        float v = redw[0][t] + redw[1][t] + redw[2][t] + redw[3][t];
        atomicAdd(&accum[b * 4 + t], v);
    }
}

__global__ void finalize(const float* __restrict__ accum, const void* __restrict__ hb,
                         const void* __restrict__ mc, const void* __restrict__ hyd,
                         const void* __restrict__ rc, const void* __restrict__ rotor,
                         void* __restrict__ out, const int* __restrict__ flagp) {
    int bf = *flagp;
    int t = threadIdx.x;  // 64 threads, use first 32
    if (t >= 32) return;
    int b = t >> 2, e = t & 3;
    float v = accum[t];
    if (e == 1) { float c = LD(hb, 0, bf);  v = -c * c * v; }
    else if (e == 2) { float c = LD(mc, 0, bf);  v = -c * c * v; }
    else if (e == 3) { float c = LD(hyd, 0, bf); v = -c * c * v; }
    float r = LD(rc, 0, bf);
    float den = 1.0f + r * r * LD(rotor, b, bf);
    float res = v / den;
    if (bf) ((bf16*)out)[t] = __float2bfloat16(res);
    else    ((float*)out)[t] = res;
}

extern "C" void kernel_launch(void* const* d_in, const int* in_sizes, int n_in,
                              void* d_out, int out_size, void* d_ws, size_t ws_size,
                              hipStream_t stream) {
    const void* ligand_h = d_in[0];
    const void* target_h = d_in[1];
    const void* ligand_adj = d_in[2];
    const void* target_adj = d_in[3];
    const void* interaction_indice = d_in[4];
    const void* ligand_pos = d_in[5];
    const void* target_pos = d_in[6];
    const void* rotor = d_in[7];
    const void* ligand_vdw = d_in[8];
    const void* target_vdw = d_in[9];
    const void* ligand_valid = d_in[10];
    const void* target_valid = d_in[11];
    const void* emb_W = d_in[12];
    const void* gat_W = d_in[13];
    const void* gat_Wb = d_in[14];
    const void* gat_A = d_in[15];
    const void* gat_gW = d_in[16];
    const void* gat_gb = d_in[17];
    const void* vdwA_W1 = d_in[18];
    const void* vdwA_b1 = d_in[19];
    const void* vdwA_W2 = d_in[20];
    const void* vdwA_b2 = d_in[21];
    const void* dc_W1 = d_in[22];
    const void* dc_b1 = d_in[23];
    const void* dc_W2 = d_in[24];
    const void* dc_b2 = d_in[25];
    const void* hbond_coeff = d_in[26];
    const void* metal_coeff = d_in[27];
    const void* hydrophobic_coeff = d_in[28];
    const void* rotor_coeff = d_in[29];

    float* ws = (float*)d_ws;
    size_t off = 0;
    float* lig_x = ws + off;  off += (size_t)BB * LL * DIMD;   // x unified (lig, tgt)
    float* tgt_x = ws + off;  off += (size_t)BB * TT * DIMD;
    float* h_lig = ws + off;  off += (size_t)BB * LL * DIMD;   // h unified
    float* h_tgt = ws + off;  off += (size_t)BB * TT * DIMD;
    float* hA_lig = ws + off; off += (size_t)BB * LL * DIMD;   // hA unified (= P0)
    float* hA_tgt = ws + off; off += (size_t)BB * TT * DIMD;
    float* accum = ws + off;  off += 32;
    int* flagp = (int*)(ws + off); off += 2;
    float* e_buf = ws + off;  off += (size_t)BB * TT * TT;     // e1 target; later transposes
    float* e_lig = ws + off;  off += (size_t)BB * LL * LL;     // e1 ligand
    float* e2_buf = ws + off; off += (size_t)BB * TT * TT;     // e2 target
    float* e2_lig = ws + off; off += (size_t)BB * LL * LL;     // e2 ligand
    float* part1 = ws + off;  off += (size_t)BB * (LL + TT) * DIMD; // P1 unified
    float* part2 = ws + off;  off += (size_t)BB * (LL + TT) * DIMD; // P2 unified
    float* part3 = ws + off;  off += (size_t)BB * (LL + TT) * DIMD; // P3 unified
    float* projA = ws + off;  off += (size_t)BB * (LL + TT) * DIMD; // vdwA projection out
    float* cvw   = ws + off;  off += (size_t)CV_TOTAL;         // f32 weight copies
    float* part0 = hA_lig;       // P0 aliases hA (unified: hA_lig then hA_tgt contiguous)
    // pair-MLP projection outputs
    float* ligdc = h_lig;        // dc out reuses h region (rows: lig then tgt)
    float* tgtdc = h_tgt;
    float* ligA = projA;         // vdwA out in fresh buffer (P0 race avoidance)
    float* tgtA = projA + (size_t)BB * LL * DIMD;
    // transposed target projections reuse e_buf (dead after the GAT loop)
    float* tgtdcT = e_buf;
    float* tgtAT  = e_buf + (size_t)BB * DIMD * TT;
    float* wEmb = cvw + CV_EMBW;

    init_cvt<<<(CV_TOTAL + 255) / 256, 256, 0, stream>>>(
        (const unsigned int*)emb_W, emb_W, gat_W, gat_A, gat_Wb,
        gat_gW, gat_gb, dc_W1, vdwA_W1, cvw, accum, flagp);

    // embeddings: x = h @ emb_W (both sides, one launch; out rows contiguous)
    embed_both<<<BB * (LL + TT), DIMD, 0, stream>>>(ligand_h, target_h, wEmb, lig_x, 54, flagp);

    const long ROWSPLIT = (long)BB * LL;   // multiple of 4
    for (int i = 0; i < 3; ++i) {
        // [gate of layer i-1] + h = x@W+Wb ; hA = h@A   (both sides, one launch)
        gemm_hha_gate<<<BB * (LL + TT) / 4, 256, 0, stream>>>(
            lig_x, part0, part1, part2, part3, cvw, i, i > 0 ? 1 : 0, h_lig, hA_lig);
        // e = S1 + S2 (term split over blockIdx.y; symmetric mirror writes)
        esym_both<<<dim3(TGT_TILES + LIG_TILES, 2, BB), 256, 0, stream>>>(
            hA_tgt, h_tgt, e_buf, e2_buf, hA_lig, h_lig, e_lig, e2_lig);
        att_softmax_both<<<dim3(TT / 4 + LL / 4, BB), 256, 0, stream>>>(
            e_buf, e2_buf, e_lig, e2_lig, target_adj, ligand_adj, flagp);
        hp_gemm_both<<<dim3(20, 4, BB), 256, 0, stream>>>(
            e_buf, h_tgt, e_lig, h_lig, part0, part1, part2, part3);
    }

    // final gate (layer 2) + both pair-MLP projections in one launch
    proj_gate<<<dim3(BB * (LL + TT) / 4, 2), 256, 0, stream>>>(
        lig_x, part0, part1, part2, part3, cvw, dc_b1, vdwA_b1, ROWSPLIT,
        ligdc, ligA, flagp);

    // transpose target projections for coalesced pair_energy reads (one launch)
    transpose_both<<<dim3(TT / 32, DIMD / 32, 2 * BB), 256, 0, stream>>>(
        tgtdc, tgtdcT, tgtA, tgtAT);

    pair_energy<<<dim3(LL / 2, BB), 256, 0, stream>>>(
        ligdc, tgtdcT, ligA, tgtAT, dc_W2, dc_b2, vdwA_W2, vdwA_b2,
        ligand_pos, target_pos, ligand_vdw, target_vdw,
        ligand_valid, target_valid, interaction_indice, accum, flagp);

    finalize<<<1, 64, 0, stream>>>(accum, hbond_coeff, metal_coeff,
                                   hydrophobic_coeff, rotor_coeff, rotor, d_out, flagp);
}